// Round 7
// baseline (689.182 us; speedup 1.0000x reference)
//
#include <hip/hip_runtime.h>

#define N_NODES 50000
#define N_EDGES 800000
#define NSTEPS 3
#define NBLK_SCAN 196  // ceil(50000/256)

typedef __attribute__((ext_vector_type(8))) short bf16x8;
typedef __attribute__((ext_vector_type(4))) float f32x4;

// ---------- helpers ----------

__device__ __forceinline__ float ldf(const void* p, long i, int bf) {
    if (bf) {
        unsigned int u = ((const unsigned short*)p)[i];
        u <<= 16;
        return __uint_as_float(u);
    }
    return ((const float*)p)[i];
}

// round-half-up bf16 (2 VALU ops; differs from RNE only at exact ties)
__device__ __forceinline__ unsigned short f2bf(float f) {
    return (unsigned short)((__float_as_uint(f) + 0x8000u) >> 16);
}

__device__ __forceinline__ float bf2f(unsigned short u) {
    return __uint_as_float(((unsigned int)u) << 16);
}

// packed f32x2 -> bf16x2 (RNE), single VALU op
__device__ __forceinline__ unsigned int cvtpk(float a, float b) {
    unsigned int r;
    asm("v_cvt_pk_bf16_f32 %0, %1, %2" : "=v"(r) : "v"(a), "v"(b));
    return r;
}

// jax.nn.gelu tanh-approx via sigmoid identity: 0.5x(1+tanh(z)) = x*sigmoid(2z)
__device__ __forceinline__ float gelu_f(float x) {
    float x2 = x * x;
    float m = x * fmaf(-0.10294325f, x2, -2.30220847f);
    float e = __builtin_amdgcn_exp2f(m);
    return x * __builtin_amdgcn_rcpf(1.0f + e);
}

// NOTE: bias-in-accumulator (MFMA C preload) was tried and REGRESSED (+23us stall):
// it moves the bias load to the layer head, stalling the first MFMA on L2 latency.
// Keep zero-init + epilogue adds so the bias load overlaps the MFMA chain.
__device__ __forceinline__ void zero4(f32x4 a[4]) {
#pragma unroll
    for (int t = 0; t < 4; t++) a[t] = (f32x4){0.f, 0.f, 0.f, 0.f};
}

// B-fragment bundle (one 64-col x 32-k weight chunk): named registers force live
// ranges so the compiler keeps the next chunk's loads in flight during MFMAs.
struct bfrag {
    bf16x8 f0, f1, f2, f3;
};
__device__ __forceinline__ bfrag loadB(const unsigned short* bb) {
    bfrag b;
    b.f0 = *(const bf16x8*)(bb + 0);
    b.f1 = *(const bf16x8*)(bb + 512);
    b.f2 = *(const bf16x8*)(bb + 1024);
    b.f3 = *(const bf16x8*)(bb + 1536);
    return b;
}
__device__ __forceinline__ void mfma4(f32x4 acc[4], bf16x8 a, const bfrag& b) {
    acc[0] = __builtin_amdgcn_mfma_f32_16x16x32_bf16(a, b.f0, acc[0], 0, 0, 0);
    acc[1] = __builtin_amdgcn_mfma_f32_16x16x32_bf16(a, b.f1, acc[1], 0, 0, 0);
    acc[2] = __builtin_amdgcn_mfma_f32_16x16x32_bf16(a, b.f2, acc[2], 0, 0, 0);
    acc[3] = __builtin_amdgcn_mfma_f32_16x16x32_bf16(a, b.f3, acc[3], 0, 0, 0);
}

__device__ __forceinline__ void mfma_chunk(f32x4 acc[4], bf16x8 a, const unsigned short* bb) {
    acc[0] = __builtin_amdgcn_mfma_f32_16x16x32_bf16(a, *(const bf16x8*)(bb + 0), acc[0], 0, 0, 0);
    acc[1] = __builtin_amdgcn_mfma_f32_16x16x32_bf16(a, *(const bf16x8*)(bb + 512), acc[1], 0, 0, 0);
    acc[2] = __builtin_amdgcn_mfma_f32_16x16x32_bf16(a, *(const bf16x8*)(bb + 1024), acc[2], 0, 0, 0);
    acc[3] = __builtin_amdgcn_mfma_f32_16x16x32_bf16(a, *(const bf16x8*)(bb + 1536), acc[3], 0, 0, 0);
}

// ---------- dtype detect ----------
__global__ void detect_kernel(const void* probe, int* flag) {
    if (threadIdx.x == 0 && blockIdx.x == 0) {
        unsigned int w = *(const unsigned int*)probe;
        *flag = (w == 0x3F803F80u) ? 1 : 0;
    }
}

// ---------- counting sort by receiver ----------
__global__ void hist_kernel(const int* __restrict__ receivers, int* __restrict__ counts) {
    int i = blockIdx.x * 256 + threadIdx.x;
    if (i < N_EDGES) atomicAdd(&counts[receivers[i]], 1);
}

__global__ void scan_partial(const int* __restrict__ counts, int* __restrict__ base,
                             int* __restrict__ blockSums) {
    __shared__ int sm[256];
    int b = blockIdx.x, t = threadIdx.x, i = b * 256 + t;
    int v = (i < N_NODES) ? counts[i] : 0;
    sm[t] = v;
    __syncthreads();
    for (int off = 1; off < 256; off <<= 1) {
        int x = (t >= off) ? sm[t - off] : 0;
        __syncthreads();
        sm[t] += x;
        __syncthreads();
    }
    if (i < N_NODES) base[i] = sm[t] - v;  // exclusive
    if (t == 255) blockSums[b] = sm[255];
}

__global__ void scan_tops(int* __restrict__ blockSums, int* __restrict__ tops) {
    __shared__ int sm[256];
    int t = threadIdx.x;
    int v = (t < NBLK_SCAN) ? blockSums[t] : 0;
    sm[t] = v;
    __syncthreads();
    for (int off = 1; off < 256; off <<= 1) {
        int x = (t >= off) ? sm[t - off] : 0;
        __syncthreads();
        sm[t] += x;
        __syncthreads();
    }
    if (t < NBLK_SCAN) tops[t] = sm[t] - v;
}

__global__ void scan_add(int* __restrict__ base, const int* __restrict__ tops,
                         int* __restrict__ cursor) {
    int b = blockIdx.x, i = b * 256 + threadIdx.x;
    if (i < N_NODES) {
        int v = base[i] + tops[b];
        base[i] = v;
        cursor[i] = v;
    }
}

__global__ void scatter_kernel(const int* __restrict__ senders,
                               const int* __restrict__ receivers, int* __restrict__ cursor,
                               int* __restrict__ ss, int* __restrict__ rsrt,
                               int* __restrict__ perm) {
    int i = blockIdx.x * 256 + threadIdx.x;
    if (i < N_EDGES) {
        int r = receivers[i];
        int pos = atomicAdd(&cursor[r], 1);
        ss[pos] = senders[i];
        rsrt[pos] = r;
        perm[pos] = i;
    }
}

// ---------- fused weight prep ----------
// Packed stored-order scheme: every internal 64-wide tensor (h panels, e_lat, n_bf,
// n_lat, recvbuf) stores original column sigma(p)=16*(p&3)+(p>>2) at position p, so
// each lane's 4 acc values are one contiguous b64/b128 write. Consumers are fixed
// here by permuting weight ROWS within each 64-block: slot k -> source row
// (k & ~63) | sigma(k & 63).
struct PrepPtrs {
    const void* W[14];
    const void* eb0;
    const void* nb0;
    const void* glob;
};

#define PREP_WTOTAL 139264
__global__ void prep_all(PrepPtrs p, unsigned short* WbBase, float* b0eff_e, float* b0eff_n,
                         const int* __restrict__ flagp) {
    const int totals[14] = {36864, 12288, 12288, 24576, 12288, 12288, 2048,
                            4096,  4096,  2048,  4096,  4096,  4096,  4096};
    const int ksrc[14] = {192, 64, 64, 128, 64, 64, 7, 64, 64, 4, 64, 64, 64, 64};
    const int sstride[14] = {12416, 4096, 4096, 8320, 4096, 4096, 448,
                             4096,  4096, 256,  4096, 4096, 4096, 4096};
    const int nch[14] = {6, 2, 2, 4, 2, 2, 1, 2, 2, 1, 2, 2, 2, 2};
    // matrices whose INPUT comes from a packed-format tensor -> permute rows.
    // 0=eW0 (e|Ns|Nr all packed), 3=nW0 (n|recv packed), hidden/decoder layers read
    // packed h panels. 6=enW0, 9=eeW0 read RAW inputs.
    const int rowperm[14] = {1, 1, 1, 1, 1, 1, 0, 1, 1, 0, 1, 1, 1, 1};

    const int bf = *flagp;
    int i = blockIdx.x * 256 + threadIdx.x;
    if (i < PREP_WTOTAL) {
        int e = 0, base = 0;
        while (i >= base + totals[e]) { base += totals[e]; e++; }
        int il = i - base;
        int j = il & 7, lane = (il >> 3) & 63, t = (il >> 9) & 3;
        int c = (il >> 11) % nch[e], s = il / (2048 * nch[e]);
        int k = c * 32 + (lane >> 4) * 8 + j;
        int col = t * 16 + (lane & 15);
        int ks = k;
        if (rowperm[e]) {
            int kb = k & 63;
            ks = (k & ~63) | (((kb & 3) << 4) | (kb >> 2));
        }
        WbBase[i] = (k < ksrc[e]) ? f2bf(ldf(p.W[e], (long)s * sstride[e] + (long)ks * 64 + col, bf))
                                  : (unsigned short)0;
    } else if (i < PREP_WTOTAL + 384) {
        int i2 = i - PREP_WTOTAL;
        float g0 = ldf(p.glob, 0, bf), g1 = ldf(p.glob, 1, bf);
        if (i2 < 192) {
            int s = i2 >> 6, col = i2 & 63;
            b0eff_e[i2] = ldf(p.eb0, i2, bf) + g0 * ldf(p.W[0], (long)s * 12416 + 192 * 64 + col, bf)
                                             + g1 * ldf(p.W[0], (long)s * 12416 + 193 * 64 + col, bf);
        } else {
            int il = i2 - 192;
            int s = il >> 6, col = il & 63;
            b0eff_n[il] = ldf(p.nb0, il, bf) + g0 * ldf(p.W[3], (long)s * 8320 + 128 * 64 + col, bf)
                                             + g1 * ldf(p.W[3], (long)s * 8320 + 129 * 64 + col, bf);
        }
    }
}

// ---------- node embedder (MFMA): [R, 7] -> MLP(7,64,64,64); 0 barriers ----------
// Outputs n_lat (f32) and n_bf (bf16) in PACKED stored order (internal format).
template <int DIN, int OUT_BF>
__global__ __launch_bounds__(256) void embed_mfma(
    const void* __restrict__ xin, const unsigned short* __restrict__ Wb0, const void* b0,
    const unsigned short* __restrict__ Wb1, const void* b1,
    const unsigned short* __restrict__ Wb2, const void* b2, void* __restrict__ outp,
    unsigned short* __restrict__ out_bf, const int* __restrict__ perm, int R,
    const int* __restrict__ flagp) {
    __shared__ __align__(16) unsigned short Xs[64 * 40];
    __shared__ __align__(16) unsigned short hbuf[64 * 72];  // per-wave 16-row panels
    const int bf = *flagp;
    const int tid = threadIdx.x;
    const long rb = (long)blockIdx.x * 64;
    const int lane = tid & 63, w = tid >> 6, q = lane >> 4, l15 = lane & 15;
    const int arow = 16 * w + l15, aoff = q * 8;
    unsigned short* hw = hbuf + w * 16 * 72;

    {  // stage own wave's 16 rows
        int r = tid >> 2, seg = tid & 3;
        long idx = rb + r;
        long src = (perm != nullptr && idx < R) ? (long)perm[idx] : idx;
        unsigned short u[8];
#pragma unroll
        for (int j = 0; j < 8; j++) {
            int col = seg * 8 + j;
            u[j] = (col < DIN && idx < R) ? f2bf(ldf(xin, src * DIN + col, bf)) : (unsigned short)0;
        }
        *(uint4*)&Xs[r * 40 + seg * 8] = *(uint4*)u;
    }
    // no barrier: own-wave rows only

    f32x4 acc[4];
    zero4(acc);
    {
        bf16x8 a = *(const bf16x8*)&Xs[arow * 40 + aoff];
        mfma_chunk(acc, a, Wb0 + lane * 8);
        float bb[4];
#pragma unroll
        for (int t = 0; t < 4; t++) bb[t] = ldf(b0, t * 16 + l15, bf);
#pragma unroll
        for (int reg = 0; reg < 4; reg++) {
            uint2 v;
            v.x = cvtpk(gelu_f(acc[0][reg] + bb[0]), gelu_f(acc[1][reg] + bb[1]));
            v.y = cvtpk(gelu_f(acc[2][reg] + bb[2]), gelu_f(acc[3][reg] + bb[3]));
            *(uint2*)&hw[(q * 4 + reg) * 72 + l15 * 4] = v;  // packed panel
        }
    }
    zero4(acc);
    {
        bfrag wA = loadB(Wb1 + lane * 8);
        bfrag wB = loadB(Wb1 + 2048 + lane * 8);
        bf16x8 a0 = *(const bf16x8*)&hw[l15 * 72 + aoff];
        bf16x8 a1 = *(const bf16x8*)&hw[l15 * 72 + 32 + aoff];
        mfma4(acc, a0, wA);
        mfma4(acc, a1, wB);
        float bb[4];
#pragma unroll
        for (int t = 0; t < 4; t++) bb[t] = ldf(b1, t * 16 + l15, bf);
#pragma unroll
        for (int reg = 0; reg < 4; reg++) {
            uint2 v;
            v.x = cvtpk(gelu_f(acc[0][reg] + bb[0]), gelu_f(acc[1][reg] + bb[1]));
            v.y = cvtpk(gelu_f(acc[2][reg] + bb[2]), gelu_f(acc[3][reg] + bb[3]));
            *(uint2*)&hw[(q * 4 + reg) * 72 + l15 * 4] = v;
        }
    }
    zero4(acc);
    {
        bfrag wA = loadB(Wb2 + lane * 8);
        bfrag wB = loadB(Wb2 + 2048 + lane * 8);
        bf16x8 a0 = *(const bf16x8*)&hw[l15 * 72 + aoff];
        bf16x8 a1 = *(const bf16x8*)&hw[l15 * 72 + 32 + aoff];
        mfma4(acc, a0, wA);
        mfma4(acc, a1, wB);
    }
    float bb[4];
#pragma unroll
    for (int t = 0; t < 4; t++) bb[t] = ldf(b2, t * 16 + l15, bf);
    if (OUT_BF) {
#pragma unroll
        for (int reg = 0; reg < 4; reg++) {
            uint2 v;
            v.x = cvtpk(acc[0][reg] + bb[0], acc[1][reg] + bb[1]);
            v.y = cvtpk(acc[2][reg] + bb[2], acc[3][reg] + bb[3]);
            *(uint2*)&hw[(q * 4 + reg) * 72 + l15 * 4] = v;  // packed
        }
#pragma unroll
        for (int p = 0; p < 2; p++) {
            int r = 16 * w + p * 8 + (lane >> 3), o = lane & 7;
            long idx = rb + r;
            if (idx < R)
                *(uint4*)&((unsigned short*)outp)[idx * 64 + o * 8] =
                    *(const uint4*)&hbuf[r * 72 + o * 8];
        }
    } else {
#pragma unroll
        for (int reg = 0; reg < 4; reg++) {
            long idx = rb + 16 * w + q * 4 + reg;
            if (idx < R) {
                float4 v4 = make_float4(acc[0][reg] + bb[0], acc[1][reg] + bb[1],
                                        acc[2][reg] + bb[2], acc[3][reg] + bb[3]);
                *(float4*)&((float*)outp)[idx * 64 + l15 * 4] = v4;  // packed f32
                uint2 v;
                v.x = cvtpk(v4.x, v4.y);
                v.y = cvtpk(v4.z, v4.w);
                *(uint2*)&out_bf[idx * 64 + l15 * 4] = v;  // packed bf16
            }
        }
    }
}

// ---------- edge step (MFMA + sorted receivers), 1 barrier, 26880 B LDS ----------
// NsNr LDS staging kept: it is the TRANSPOSE that makes the sender/receiver gather
// coalesced (8 consecutive lanes per 128B row). n_bf / e_lat are packed stored-order
// formats; weight rows permuted to match in prep. Weight B-fragments are explicitly
// double-buffered (named regs) so chunk c+1's global loads fly during chunk c's
// MFMAs -- at VGPR=48 the compiler chose a minimal-register schedule that stalled
// each chunk on L2 latency. S0: edge embedder fused in. LAST: skip residual/LN/e-store.
#define EST 72
#define NST 68
template <int S0, int LAST>
__global__ __launch_bounds__(256) void edge_step(
    unsigned short* __restrict__ e_lat, const unsigned short* __restrict__ n_bf,
    const int* __restrict__ ss, const int* __restrict__ rsrt, const int* __restrict__ perm,
    const void* __restrict__ xe_raw, const unsigned short* __restrict__ We0, const void* eb0_,
    const unsigned short* __restrict__ We1, const void* eb1_,
    const unsigned short* __restrict__ We2, const void* eb2_,
    const unsigned short* __restrict__ Wb0, const unsigned short* __restrict__ Wb1,
    const unsigned short* __restrict__ Wb2, const float* __restrict__ b0eff, const void* b1,
    const void* b2, const void* lnsc, const void* lnbi, float* __restrict__ recvbuf, int s,
    const int* __restrict__ flagp) {
    __shared__ __align__(16) unsigned short Ee[64 * EST];     // 9216 B
    __shared__ __align__(16) unsigned short NsNr[128 * NST];  // 17408 B
    __shared__ int rcvs[64];
    float* newe = (float*)NsNr;  // wave w segment: 16 rows x 68 floats (4352 B)

    const int bf = *flagp;
    const int tid = threadIdx.x;
    const long rb = (long)blockIdx.x * 64;
    const int lane = tid & 63, w = tid >> 6, q = lane >> 4, l15 = lane & 15;
    const int arow = 16 * w + l15, aoff = q * 8;
    unsigned short* hw = Ee + w * 16 * EST;  // wave-private h panel (own e rows)

    // ---- wave-private staging: own 16 rows of Ns / Nr (coalesced 128B rows) ----
#pragma unroll
    for (int p = 0; p < 2; p++) {
        int r = 16 * w + p * 8 + (lane >> 3), o = lane & 7;
        long node = ss[rb + r];
        *(uint4*)&NsNr[r * NST + o * 8] = ((const uint4*)(n_bf + node * 64))[o];
    }
#pragma unroll
    for (int p = 0; p < 2; p++) {
        int r = 16 * w + p * 8 + (lane >> 3), o = lane & 7;
        long node = rsrt[rb + r];
        *(uint4*)&NsNr[(64 + r) * NST + o * 8] = ((const uint4*)(n_bf + node * 64))[o];
    }
    if (lane < 16) rcvs[16 * w + lane] = rsrt[rb + 16 * w + lane];
    // no B1: all reads below touch only own-wave rows

    float ein[4][4];
    f32x4 acc[4];

    if (S0) {
        // ---- inline edge embedder: raw edges [E,4] -> e (ein f32 regs + packed Ee);
        // runs while the NsNr gathers are in flight ----
        zero4(acc);
        {
            bf16x8 a = (bf16x8){0, 0, 0, 0, 0, 0, 0, 0};
            if (q == 0) {
                long src = perm[rb + arow];
                unsigned short u[8] = {0, 0, 0, 0, 0, 0, 0, 0};
#pragma unroll
                for (int j = 0; j < 4; j++) u[j] = f2bf(ldf(xe_raw, src * 4 + j, bf));
                a = *(const bf16x8*)u;
            }
            mfma_chunk(acc, a, We0 + lane * 8);
            float bb[4];
#pragma unroll
            for (int t = 0; t < 4; t++) bb[t] = ldf(eb0_, t * 16 + l15, bf);
#pragma unroll
            for (int reg = 0; reg < 4; reg++) {
                uint2 v;
                v.x = cvtpk(gelu_f(acc[0][reg] + bb[0]), gelu_f(acc[1][reg] + bb[1]));
                v.y = cvtpk(gelu_f(acc[2][reg] + bb[2]), gelu_f(acc[3][reg] + bb[3]));
                *(uint2*)&hw[(q * 4 + reg) * EST + l15 * 4] = v;
            }
        }
        zero4(acc);
        {
            bfrag wA = loadB(We1 + lane * 8);
            bfrag wB = loadB(We1 + 2048 + lane * 8);
            bf16x8 a0 = *(const bf16x8*)&hw[l15 * EST + aoff];
            bf16x8 a1 = *(const bf16x8*)&hw[l15 * EST + 32 + aoff];
            mfma4(acc, a0, wA);
            mfma4(acc, a1, wB);
            float bb[4];
#pragma unroll
            for (int t = 0; t < 4; t++) bb[t] = ldf(eb1_, t * 16 + l15, bf);
#pragma unroll
            for (int reg = 0; reg < 4; reg++) {
                uint2 v;
                v.x = cvtpk(gelu_f(acc[0][reg] + bb[0]), gelu_f(acc[1][reg] + bb[1]));
                v.y = cvtpk(gelu_f(acc[2][reg] + bb[2]), gelu_f(acc[3][reg] + bb[3]));
                *(uint2*)&hw[(q * 4 + reg) * EST + l15 * 4] = v;
            }
        }
        zero4(acc);
        {
            bfrag wA = loadB(We2 + lane * 8);
            bfrag wB = loadB(We2 + 2048 + lane * 8);
            bf16x8 a0 = *(const bf16x8*)&hw[l15 * EST + aoff];
            bf16x8 a1 = *(const bf16x8*)&hw[l15 * EST + 32 + aoff];
            mfma4(acc, a0, wA);
            mfma4(acc, a1, wB);
            float bb[4];
#pragma unroll
            for (int t = 0; t < 4; t++) bb[t] = ldf(eb2_, t * 16 + l15, bf);
#pragma unroll
            for (int reg = 0; reg < 4; reg++) {
#pragma unroll
                for (int t = 0; t < 4; t++) ein[reg][t] = acc[t][reg] + bb[t];
                uint2 v;
                v.x = cvtpk(ein[reg][0], ein[reg][1]);
                v.y = cvtpk(ein[reg][2], ein[reg][3]);
                *(uint2*)&Ee[(16 * w + q * 4 + reg) * EST + l15 * 4] = v;
            }
        }
    } else {
        // ---- stage own wave's 16 e rows from e_lat (packed format) ----
#pragma unroll
        for (int p = 0; p < 2; p++) {
            int r = 16 * w + p * 8 + (lane >> 3), o = lane & 7;
            *(uint4*)&Ee[r * EST + o * 8] = ((const uint4*)(e_lat + (rb + r) * 64))[o];
        }
        if (!LAST) {  // residual preload: one b64 per row
#pragma unroll
            for (int reg = 0; reg < 4; reg++) {
                uint2 pv = *(const uint2*)&Ee[(16 * w + q * 4 + reg) * EST + l15 * 4];
                ein[reg][0] = __uint_as_float(pv.x << 16);
                ein[reg][1] = __uint_as_float(pv.x & 0xffff0000u);
                ein[reg][2] = __uint_as_float(pv.y << 16);
                ein[reg][3] = __uint_as_float(pv.y & 0xffff0000u);
            }
        }
    }

    zero4(acc);
    {  // layer 0: K=192 from Ee | Ns | Nr; B-frags 2-deep double-buffered
        const unsigned short* B = Wb0 + (long)s * 6 * 2048 + lane * 8;
        bfrag wA = loadB(B);
        bfrag wB = loadB(B + 2048);
        bf16x8 a0 = *(const bf16x8*)&Ee[arow * EST + aoff];
        bf16x8 a1 = *(const bf16x8*)&Ee[arow * EST + 32 + aoff];
        bf16x8 a2 = *(const bf16x8*)&NsNr[arow * NST + aoff];
        bf16x8 a3 = *(const bf16x8*)&NsNr[arow * NST + 32 + aoff];
        bf16x8 a4 = *(const bf16x8*)&NsNr[(64 + arow) * NST + aoff];
        bf16x8 a5 = *(const bf16x8*)&NsNr[(64 + arow) * NST + 32 + aoff];
        mfma4(acc, a0, wA);
        wA = loadB(B + 2 * 2048);
        mfma4(acc, a1, wB);
        wB = loadB(B + 3 * 2048);
        mfma4(acc, a2, wA);
        wA = loadB(B + 4 * 2048);
        mfma4(acc, a3, wB);
        wB = loadB(B + 5 * 2048);
        mfma4(acc, a4, wA);
        mfma4(acc, a5, wB);
        float bb[4];
#pragma unroll
        for (int t = 0; t < 4; t++) bb[t] = b0eff[s * 64 + t * 16 + l15];
#pragma unroll
        for (int reg = 0; reg < 4; reg++) {
            uint2 v;
            v.x = cvtpk(gelu_f(acc[0][reg] + bb[0]), gelu_f(acc[1][reg] + bb[1]));
            v.y = cvtpk(gelu_f(acc[2][reg] + bb[2]), gelu_f(acc[3][reg] + bb[3]));
            *(uint2*)&hw[(q * 4 + reg) * EST + l15 * 4] = v;
        }
    }
    zero4(acc);
    {  // layer 1 (wave-private h); both B chunks preloaded
        const unsigned short* B = Wb1 + (long)s * 2 * 2048 + lane * 8;
        bfrag wA = loadB(B);
        bfrag wB = loadB(B + 2048);
        bf16x8 a0 = *(const bf16x8*)&hw[l15 * EST + aoff];
        bf16x8 a1 = *(const bf16x8*)&hw[l15 * EST + 32 + aoff];
        mfma4(acc, a0, wA);
        mfma4(acc, a1, wB);
        float bb[4];
#pragma unroll
        for (int t = 0; t < 4; t++) bb[t] = ldf(b1, (long)s * 64 + t * 16 + l15, bf);
#pragma unroll
        for (int reg = 0; reg < 4; reg++) {
            uint2 v;
            v.x = cvtpk(gelu_f(acc[0][reg] + bb[0]), gelu_f(acc[1][reg] + bb[1]));
            v.y = cvtpk(gelu_f(acc[2][reg] + bb[2]), gelu_f(acc[3][reg] + bb[3]));
            *(uint2*)&hw[(q * 4 + reg) * EST + l15 * 4] = v;
        }
    }
    zero4(acc);
    {  // layer 2; both B chunks preloaded
        const unsigned short* B = Wb2 + (long)s * 2 * 2048 + lane * 8;
        bfrag wA = loadB(B);
        bfrag wB = loadB(B + 2048);
        bf16x8 a0 = *(const bf16x8*)&hw[l15 * EST + aoff];
        bf16x8 a1 = *(const bf16x8*)&hw[l15 * EST + 32 + aoff];
        mfma4(acc, a0, wA);
        mfma4(acc, a1, wB);
    }
    __syncthreads();  // B2: all layer-0 NsNr reads drained before newe overlay

    // ---- fin = new_e + b2 (bias load overlaps layer-2 chain); packed newe ----
    float fin[4][4];
    {
        float bb[4];
#pragma unroll
        for (int t = 0; t < 4; t++) bb[t] = ldf(b2, (long)s * 64 + t * 16 + l15, bf);
#pragma unroll
        for (int reg = 0; reg < 4; reg++)
#pragma unroll
            for (int t = 0; t < 4; t++) fin[reg][t] = acc[t][reg] + bb[t];
    }
    float lsc[4], lbi[4];
    if (!LAST) {
#pragma unroll
        for (int t = 0; t < 4; t++) {
            lsc[t] = ldf(lnsc, (long)s * 64 + t * 16 + l15, bf);
            lbi[t] = ldf(lnbi, (long)s * 64 + t * 16 + l15, bf);
        }
    }
#pragma unroll
    for (int reg = 0; reg < 4; reg++) {
        const int lr = q * 4 + reg;
        // packed stored-order newe row: one b128 instead of 16 b32
        *(float4*)&newe[w * 1088 + lr * 68 + l15 * 4] =
            make_float4(fin[reg][0], fin[reg][1], fin[reg][2], fin[reg][3]);
        if (!LAST) {
            float u[4], ssum = 0.f;
#pragma unroll
            for (int t = 0; t < 4; t++) {
                u[t] = ein[reg][t] + fin[reg][t];
                ssum += u[t];
            }
#pragma unroll
            for (int m = 1; m < 16; m <<= 1) ssum += __shfl_xor(ssum, m, 64);
            const float mu = ssum * (1.0f / 64.0f);
            float d[4], vv = 0.f;
#pragma unroll
            for (int t = 0; t < 4; t++) { d[t] = u[t] - mu; vv += d[t] * d[t]; }
#pragma unroll
            for (int m = 1; m < 16; m <<= 1) vv += __shfl_xor(vv, m, 64);
            const float rs = rsqrtf(vv * (1.0f / 64.0f) + 1e-6f);
            uint2 v;
            v.x = cvtpk(d[0] * rs * lsc[0] + lbi[0], d[1] * rs * lsc[1] + lbi[1]);
            v.y = cvtpk(d[2] * rs * lsc[2] + lbi[2], d[3] * rs * lsc[3] + lbi[3]);
            *(uint2*)&Ee[(16 * w + lr) * EST + l15 * 4] = v;  // packed LN'd e
        }
    }
    // no B3: e-store reads only own-wave Ee rows

    if (!LAST) {  // wave-private vectorized e store (packed format)
#pragma unroll
        for (int p = 0; p < 2; p++) {
            int r = 16 * w + p * 8 + (lane >> 3), o = lane & 7;
            *(uint4*)&e_lat[(rb + r) * 64 + o * 8] = *(const uint4*)&Ee[r * EST + o * 8];
        }
    }
    // ---- run-segmented scatter-add (sorted receivers; recvbuf in stored order) ----
    {
        const int col = tid & 63, g = tid >> 6;
        float a = 0.f;
#pragma unroll
        for (int rr = 0; rr < 16; rr++) {
            const int r = 16 * g + rr;
            a += newe[g * 1088 + rr * 68 + col];
            if (rr == 15 || rcvs[r + 1] != rcvs[r]) {  // wave-uniform branch
                atomicAdd(&recvbuf[(long)rcvs[r] * 64 + col], a);
                a = 0.f;
            }
        }
    }
}

// ---------- node update (MFMA), 0 barriers; FINAL fuses the decoder ----------
#define NXS 136
template <int FINAL>
__global__ __launch_bounds__(256) void node_update_mfma(
    float* __restrict__ n_lat, unsigned short* __restrict__ n_bf, float* __restrict__ recvbuf,
    const unsigned short* __restrict__ Wb0, const float* __restrict__ b0eff,
    const unsigned short* __restrict__ Wb1, const void* b1,
    const unsigned short* __restrict__ Wb2, const void* b2, const void* lnsc,
    const void* lnbi, const unsigned short* __restrict__ WbD0, const void* db0,
    const unsigned short* __restrict__ WbD1, const void* db1, const void* dW2,
    const void* db2, void* __restrict__ outp, int s, const int* __restrict__ flagp) {
    __shared__ __align__(16) unsigned short Xs[64 * NXS];   // 17408 B
    __shared__ __align__(16) unsigned short hbuf[64 * 72];  // per-wave panels
    const int bf = *flagp;
    const int tid = threadIdx.x;
    const long rb = (long)blockIdx.x * 64;
    const int lane = tid & 63, w = tid >> 6, q = lane >> 4, l15 = lane & 15;
    const int arow = 16 * w + l15, aoff = q * 8;
    unsigned short* hw = hbuf + w * 16 * 72;

#pragma unroll
    for (int p = 0; p < 2; p++) {
        int r = 16 * w + p * 8 + (lane >> 3), o = lane & 7;
        long idx = rb + r;
        uint4 v = {0u, 0u, 0u, 0u};
        if (idx < N_NODES) v = ((const uint4*)(n_bf + idx * 64))[o];
        *(uint4*)&Xs[r * NXS + o * 8] = v;
    }
#pragma unroll
    for (int p = 0; p < 2; p++) {
        int r = 16 * w + p * 8 + (lane >> 3), o = lane & 7;
        long idx = rb + r;
        uint4 v = {0u, 0u, 0u, 0u};
        if (idx < N_NODES) {
            const float* src = recvbuf + idx * 64 + o * 8;
            float4 x0 = *(const float4*)src, x1 = *(const float4*)(src + 4);
            v.x = cvtpk(x0.x, x0.y);
            v.y = cvtpk(x0.z, x0.w);
            v.z = cvtpk(x1.x, x1.y);
            v.w = cvtpk(x1.z, x1.w);
        }
        *(uint4*)&Xs[r * NXS + 64 + o * 8] = v;
    }
    // no barrier: own-wave rows only

    f32x4 acc[4];
    zero4(acc);
    {  // layer 0: K=128 (glob folded into b0eff); B-frags 2-deep
        const unsigned short* B = Wb0 + (long)s * 4 * 2048 + lane * 8;
        bfrag wA = loadB(B);
        bfrag wB = loadB(B + 2048);
        bf16x8 a0 = *(const bf16x8*)&Xs[arow * NXS + aoff];
        bf16x8 a1 = *(const bf16x8*)&Xs[arow * NXS + 32 + aoff];
        bf16x8 a2 = *(const bf16x8*)&Xs[arow * NXS + 64 + aoff];
        bf16x8 a3 = *(const bf16x8*)&Xs[arow * NXS + 96 + aoff];
        mfma4(acc, a0, wA);
        wA = loadB(B + 2 * 2048);
        mfma4(acc, a1, wB);
        wB = loadB(B + 3 * 2048);
        mfma4(acc, a2, wA);
        mfma4(acc, a3, wB);
        float bb[4];
#pragma unroll
        for (int t = 0; t < 4; t++) bb[t] = b0eff[s * 64 + t * 16 + l15];
#pragma unroll
        for (int reg = 0; reg < 4; reg++) {
            uint2 v;
            v.x = cvtpk(gelu_f(acc[0][reg] + bb[0]), gelu_f(acc[1][reg] + bb[1]));
            v.y = cvtpk(gelu_f(acc[2][reg] + bb[2]), gelu_f(acc[3][reg] + bb[3]));
            *(uint2*)&hw[(q * 4 + reg) * 72 + l15 * 4] = v;
        }
    }
    zero4(acc);
    {
        const unsigned short* B = Wb1 + (long)s * 2 * 2048 + lane * 8;
        bfrag wA = loadB(B);
        bfrag wB = loadB(B + 2048);
        bf16x8 a0 = *(const bf16x8*)&hw[l15 * 72 + aoff];
        bf16x8 a1 = *(const bf16x8*)&hw[l15 * 72 + 32 + aoff];
        mfma4(acc, a0, wA);
        mfma4(acc, a1, wB);
        float bb[4];
#pragma unroll
        for (int t = 0; t < 4; t++) bb[t] = ldf(b1, (long)s * 64 + t * 16 + l15, bf);
#pragma unroll
        for (int reg = 0; reg < 4; reg++) {
            uint2 v;
            v.x = cvtpk(gelu_f(acc[0][reg] + bb[0]), gelu_f(acc[1][reg] + bb[1]));
            v.y = cvtpk(gelu_f(acc[2][reg] + bb[2]), gelu_f(acc[3][reg] + bb[3]));
            *(uint2*)&hw[(q * 4 + reg) * 72 + l15 * 4] = v;
        }
    }
    zero4(acc);
    {
        const unsigned short* B = Wb2 + (long)s * 2 * 2048 + lane * 8;
        bfrag wA = loadB(B);
        bfrag wB = loadB(B + 2048);
        bf16x8 a0 = *(const bf16x8*)&hw[l15 * 72 + aoff];
        bf16x8 a1 = *(const bf16x8*)&hw[l15 * 72 + 32 + aoff];
        mfma4(acc, a0, wA);
        mfma4(acc, a1, wB);
    }
    float b2v[4], lsc[4], lbi[4];
#pragma unroll
    for (int t = 0; t < 4; t++) {
        b2v[t] = ldf(b2, (long)s * 64 + t * 16 + l15, bf);
        lsc[t] = ldf(lnsc, (long)s * 64 + t * 16 + l15, bf);
        lbi[t] = ldf(lnbi, (long)s * 64 + t * 16 + l15, bf);
    }
#pragma unroll
    for (int reg = 0; reg < 4; reg++) {
        const int rowl = 16 * w + q * 4 + reg;
        const long idx = rb + rowl;
        const bool valid = idx < N_NODES;
        float4 xn4 = make_float4(0.f, 0.f, 0.f, 0.f);
        if (valid) xn4 = *(const float4*)&n_lat[idx * 64 + l15 * 4];  // packed f32
        float u[4], ssum = 0.f;
        u[0] = xn4.x + acc[0][reg] + b2v[0];
        u[1] = xn4.y + acc[1][reg] + b2v[1];
        u[2] = xn4.z + acc[2][reg] + b2v[2];
        u[3] = xn4.w + acc[3][reg] + b2v[3];
#pragma unroll
        for (int t = 0; t < 4; t++) ssum += u[t];
#pragma unroll
        for (int m = 1; m < 16; m <<= 1) ssum += __shfl_xor(ssum, m, 64);
        const float mu = ssum * (1.0f / 64.0f);
        float d[4], vv = 0.f;
#pragma unroll
        for (int t = 0; t < 4; t++) { d[t] = u[t] - mu; vv += d[t] * d[t]; }
#pragma unroll
        for (int m = 1; m < 16; m <<= 1) vv += __shfl_xor(vv, m, 64);
        const float rs = rsqrtf(vv * (1.0f / 64.0f) + 1e-6f);
        if (FINAL) {
            // n is consumed only by the decoder -> packed panel, no global n stores
            uint2 v;
            v.x = cvtpk(d[0] * rs * lsc[0] + lbi[0], d[1] * rs * lsc[1] + lbi[1]);
            v.y = cvtpk(d[2] * rs * lsc[2] + lbi[2], d[3] * rs * lsc[3] + lbi[3]);
            *(uint2*)&hw[(q * 4 + reg) * 72 + l15 * 4] = v;
        } else if (valid) {
            float4 v4 = make_float4(d[0] * rs * lsc[0] + lbi[0], d[1] * rs * lsc[1] + lbi[1],
                                    d[2] * rs * lsc[2] + lbi[2], d[3] * rs * lsc[3] + lbi[3]);
            *(float4*)&n_lat[idx * 64 + l15 * 4] = v4;  // packed f32
            uint2 v;
            v.x = cvtpk(v4.x, v4.y);
            v.y = cvtpk(v4.z, v4.w);
            *(uint2*)&n_bf[idx * 64 + l15 * 4] = v;  // packed bf16
            *(float4*)&recvbuf[idx * 64 + l15 * 4] = make_float4(0.f, 0.f, 0.f, 0.f);
        }
    }
    if (FINAL) {  // ---- fused decoder: MLP(64,64,64,3) on the packed LN panel ----
        zero4(acc);
        {
            bfrag wA = loadB(WbD0 + lane * 8);
            bfrag wB = loadB(WbD0 + 2048 + lane * 8);
            bf16x8 a0 = *(const bf16x8*)&hw[l15 * 72 + aoff];
            bf16x8 a1 = *(const bf16x8*)&hw[l15 * 72 + 32 + aoff];
            mfma4(acc, a0, wA);
            mfma4(acc, a1, wB);
            float bb[4];
#pragma unroll
            for (int t = 0; t < 4; t++) bb[t] = ldf(db0, t * 16 + l15, bf);
#pragma unroll
            for (int reg = 0; reg < 4; reg++) {
                uint2 v;
                v.x = cvtpk(gelu_f(acc[0][reg] + bb[0]), gelu_f(acc[1][reg] + bb[1]));
                v.y = cvtpk(gelu_f(acc[2][reg] + bb[2]), gelu_f(acc[3][reg] + bb[3]));
                *(uint2*)&hw[(q * 4 + reg) * 72 + l15 * 4] = v;
            }
        }
        zero4(acc);
        {
            bfrag wA = loadB(WbD1 + lane * 8);
            bfrag wB = loadB(WbD1 + 2048 + lane * 8);
            bf16x8 a0 = *(const bf16x8*)&hw[l15 * 72 + aoff];
            bf16x8 a1 = *(const bf16x8*)&hw[l15 * 72 + 32 + aoff];
            mfma4(acc, a0, wA);
            mfma4(acc, a1, wB);
            float bb[4];
#pragma unroll
            for (int t = 0; t < 4; t++) bb[t] = ldf(db1, t * 16 + l15, bf);
#pragma unroll
            for (int reg = 0; reg < 4; reg++) {
                uint2 v;
                v.x = cvtpk(gelu_f(acc[0][reg] + bb[0]), gelu_f(acc[1][reg] + bb[1]));
                v.y = cvtpk(gelu_f(acc[2][reg] + bb[2]), gelu_f(acc[3][reg] + bb[3]));
                *(uint2*)&hw[(q * 4 + reg) * 72 + l15 * 4] = v;
            }
        }
        const int col = tid & 63;
        const int r0 = w * 16;
        if (col < 3) {
            float a[16];
            const float b = ldf(db2, col, bf);
#pragma unroll
            for (int i = 0; i < 16; i++) a[i] = b;
            for (int k = 0; k < 64; k++) {
                // hw position k holds original feature sigma(k) = 16*(k&3)+(k>>2)
                const int ksrc2 = ((k & 3) << 4) | (k >> 2);
                float wv = ldf(dW2, (long)ksrc2 * 3 + col, bf);
#pragma unroll
                for (int i = 0; i < 16; i++) a[i] = fmaf(bf2f(hw[i * 72 + k]), wv, a[i]);
            }
            for (int i = 0; i < 16; i++) {
                const long idx = rb + r0 + i;
                if (idx < N_NODES) {
                    if (bf)
                        ((unsigned short*)outp)[idx * 3 + col] = f2bf(a[i]);
                    else
                        ((float*)outp)[idx * 3 + col] = a[i];
                }
            }
        }
    }
}

// ---------- launch ----------
extern "C" void kernel_launch(void* const* d_in, const int* in_sizes, int n_in, void* d_out,
                              int out_size, void* d_ws, size_t ws_size, hipStream_t stream) {
    const void* nodes = d_in[0];
    const void* edges = d_in[1];
    const void* glob = d_in[2];
    const void *enW0 = d_in[3], *enb0 = d_in[4], *enW1 = d_in[5], *enb1 = d_in[6],
               *enW2 = d_in[7], *enb2 = d_in[8];
    const void *eeW0 = d_in[9], *eeb0 = d_in[10], *eeW1 = d_in[11], *eeb1 = d_in[12],
               *eeW2 = d_in[13], *eeb2 = d_in[14];
    const void *eW0 = d_in[15], *eb0 = d_in[16], *eW1 = d_in[17], *eb1 = d_in[18],
               *eW2 = d_in[19], *eb2 = d_in[20];
    const void *nW0 = d_in[21], *nb0 = d_in[22], *nW1 = d_in[23], *nb1 = d_in[24],
               *nW2 = d_in[25], *nb2 = d_in[26];
    const void *lnns = d_in[27], *lnnb = d_in[28], *lnes = d_in[29], *lneb = d_in[30];
    const void *dW0 = d_in[31], *db0 = d_in[32], *dW1 = d_in[33], *db1 = d_in[34],
               *dW2 = d_in[35], *db2 = d_in[36];
    const int* senders = (const int*)d_in[37];
    const int* receivers = (const int*)d_in[38];

    // workspace layout
    float* n_lat = (float*)d_ws;               // 3,200,000 f32
    float* recvb = n_lat + 3200000;            // 3,200,000 f32
    float* b0eff_e = recvb + 3200000;          // 192
    float* b0eff_n = b0eff_e + 192;            // 192
    int* flag = (int*)(b0eff_n + 192);         // pad to 64 f32
    unsigned short* e_lat = (unsigned short*)(b0eff_n + 256);  // 51,200,000 bf16
    unsigned short* n_bf = e_lat + 51200000;   // 3,200,000 bf16
    unsigned short* WbBase = n_bf + 3200000;   // 139,264 bf16
    unsigned short* WbE0 = WbBase;
    unsigned short* WbE1 = WbBase + 36864;
    unsigned short* WbE2 = WbBase + 49152;
    unsigned short* WbN0 = WbBase + 61440;
    unsigned short* WbN1 = WbBase + 86016;
    unsigned short* WbN2 = WbBase + 98304;
    unsigned short* WbNE0 = WbBase + 110592;
    unsigned short* WbNE1 = WbBase + 112640;
    unsigned short* WbNE2 = WbBase + 116736;
    unsigned short* WbEE0 = WbBase + 120832;
    unsigned short* WbEE1 = WbBase + 122880;
    unsigned short* WbEE2 = WbBase + 126976;
    unsigned short* WbD0 = WbBase + 131072;
    unsigned short* WbD1 = WbBase + 135168;
    int* counts = (int*)(WbBase + 139264 + 64);  // aligned scratch
    int* sbase = counts + N_NODES;
    int* cursor = sbase + N_NODES;
    int* blockSums = cursor + N_NODES;  // 256
    int* tops = blockSums + 256;        // 256
    int* ss = tops + 256;               // N_EDGES
    int* rsrt = ss + N_EDGES;           // N_EDGES
    int* perm = rsrt + N_EDGES;         // N_EDGES

    detect_kernel<<<1, 64, 0, stream>>>(lnns, flag);

    PrepPtrs pp;
    pp.W[0] = eW0;  pp.W[1] = eW1;  pp.W[2] = eW2;
    pp.W[3] = nW0;  pp.W[4] = nW1;  pp.W[5] = nW2;
    pp.W[6] = enW0; pp.W[7] = enW1; pp.W[8] = enW2;
    pp.W[9] = eeW0; pp.W[10] = eeW1; pp.W[11] = eeW2;
    pp.W[12] = dW0; pp.W[13] = dW1;
    pp.eb0 = eb0; pp.nb0 = nb0; pp.glob = glob;
    prep_all<<<(PREP_WTOTAL + 384 + 255) / 256, 256, 0, stream>>>(pp, WbBase, b0eff_e, b0eff_n,
                                                                  flag);
    hipMemsetAsync(recvb, 0, (size_t)N_NODES * 64 * sizeof(float), stream);
    hipMemsetAsync(counts, 0, (size_t)N_NODES * sizeof(int), stream);

    // counting sort of edges by receiver
    hist_kernel<<<(N_EDGES + 255) / 256, 256, 0, stream>>>(receivers, counts);
    scan_partial<<<NBLK_SCAN, 256, 0, stream>>>(counts, sbase, blockSums);
    scan_tops<<<1, 256, 0, stream>>>(blockSums, tops);
    scan_add<<<NBLK_SCAN, 256, 0, stream>>>(sbase, tops, cursor);
    scatter_kernel<<<(N_EDGES + 255) / 256, 256, 0, stream>>>(senders, receivers, cursor, ss,
                                                              rsrt, perm);

    embed_mfma<7, 0><<<(N_NODES + 63) / 64, 256, 0, stream>>>(
        nodes, WbNE0, enb0, WbNE1, enb1, WbNE2, enb2, n_lat, n_bf, (const int*)nullptr,
        N_NODES, flag);

    // step 0: edge embedder fused into the edge update (no e_lat read, residual in f32)
    edge_step<1, 0><<<N_EDGES / 64, 256, 0, stream>>>(
        e_lat, n_bf, ss, rsrt, perm, edges, WbEE0, eeb0, WbEE1, eeb1, WbEE2, eeb2,
        WbE0, WbE1, WbE2, b0eff_e, eb1, eb2, lnes, lneb, recvb, 0, flag);
    node_update_mfma<0><<<(N_NODES + 63) / 64, 256, 0, stream>>>(
        n_lat, n_bf, recvb, WbN0, b0eff_n, WbN1, nb1, WbN2, nb2, lnns, lnnb,
        nullptr, nullptr, nullptr, nullptr, nullptr, nullptr, nullptr, 0, flag);

    edge_step<0, 0><<<N_EDGES / 64, 256, 0, stream>>>(
        e_lat, n_bf, ss, rsrt, perm, edges, WbEE0, eeb0, WbEE1, eeb1, WbEE2, eeb2,
        WbE0, WbE1, WbE2, b0eff_e, eb1, eb2, lnes, lneb, recvb, 1, flag);
    node_update_mfma<0><<<(N_NODES + 63) / 64, 256, 0, stream>>>(
        n_lat, n_bf, recvb, WbN0, b0eff_n, WbN1, nb1, WbN2, nb2, lnns, lnnb,
        nullptr, nullptr, nullptr, nullptr, nullptr, nullptr, nullptr, 1, flag);

    // step 2: e is dead after this step -> no LN/e-store; decoder fused into node update
    edge_step<0, 1><<<N_EDGES / 64, 256, 0, stream>>>(
        e_lat, n_bf, ss, rsrt, perm, edges, WbEE0, eeb0, WbEE1, eeb1, WbEE2, eeb2,
        WbE0, WbE1, WbE2, b0eff_e, eb1, eb2, lnes, lneb, recvb, 2, flag);
    node_update_mfma<1><<<(N_NODES + 63) / 64, 256, 0, stream>>>(
        n_lat, n_bf, recvb, WbN0, b0eff_n, WbN1, nb1, WbN2, nb2, lnns, lnnb,
        WbD0, db0, WbD1, db1, dW2, db2, d_out, 2, flag);
}

// Round 8
// 666.844 us; speedup vs baseline: 1.0335x; 1.0335x over previous
//
#include <hip/hip_runtime.h>

#define N_NODES 50000
#define N_EDGES 800000
#define NSTEPS 3
#define NBLK_SCAN 196  // ceil(50000/256)

typedef __attribute__((ext_vector_type(8))) short bf16x8;
typedef __attribute__((ext_vector_type(4))) float f32x4;

// ---------- helpers ----------

__device__ __forceinline__ float ldf(const void* p, long i, int bf) {
    if (bf) {
        unsigned int u = ((const unsigned short*)p)[i];
        u <<= 16;
        return __uint_as_float(u);
    }
    return ((const float*)p)[i];
}

// round-half-up bf16 (2 VALU ops; differs from RNE only at exact ties)
__device__ __forceinline__ unsigned short f2bf(float f) {
    return (unsigned short)((__float_as_uint(f) + 0x8000u) >> 16);
}

__device__ __forceinline__ float bf2f(unsigned short u) {
    return __uint_as_float(((unsigned int)u) << 16);
}

// packed f32x2 -> bf16x2 (RNE), single VALU op
__device__ __forceinline__ unsigned int cvtpk(float a, float b) {
    unsigned int r;
    asm("v_cvt_pk_bf16_f32 %0, %1, %2" : "=v"(r) : "v"(a), "v"(b));
    return r;
}

// jax.nn.gelu tanh-approx via sigmoid identity: 0.5x(1+tanh(z)) = x*sigmoid(2z)
__device__ __forceinline__ float gelu_f(float x) {
    float x2 = x * x;
    float m = x * fmaf(-0.10294325f, x2, -2.30220847f);
    float e = __builtin_amdgcn_exp2f(m);
    return x * __builtin_amdgcn_rcpf(1.0f + e);
}

// SCHEDULING LEDGER (both tried, both regressed -- do not retry):
// 1. bias-in-accumulator (MFMA C preload): +23us -- moves bias load to layer head,
//    first MFMA stalls on L2 latency (r5).
// 2. explicit B-fragment double-buffering via named regs (bfrag/loadB): +18us --
//    VGPR 48->56, achieved occupancy 52.8->42.6%; 6 waves/SIMD of TLP already
//    covers the L2-hot weight-load latency, forced live ranges only cost occupancy (r7).
// The compiler's minimal-register schedule at VGPR=48 is the local optimum.
__device__ __forceinline__ void zero4(f32x4 a[4]) {
#pragma unroll
    for (int t = 0; t < 4; t++) a[t] = (f32x4){0.f, 0.f, 0.f, 0.f};
}

__device__ __forceinline__ void mfma_chunk(f32x4 acc[4], bf16x8 a, const unsigned short* bb) {
    acc[0] = __builtin_amdgcn_mfma_f32_16x16x32_bf16(a, *(const bf16x8*)(bb + 0), acc[0], 0, 0, 0);
    acc[1] = __builtin_amdgcn_mfma_f32_16x16x32_bf16(a, *(const bf16x8*)(bb + 512), acc[1], 0, 0, 0);
    acc[2] = __builtin_amdgcn_mfma_f32_16x16x32_bf16(a, *(const bf16x8*)(bb + 1024), acc[2], 0, 0, 0);
    acc[3] = __builtin_amdgcn_mfma_f32_16x16x32_bf16(a, *(const bf16x8*)(bb + 1536), acc[3], 0, 0, 0);
}

// ---------- dtype detect ----------
__global__ void detect_kernel(const void* probe, int* flag) {
    if (threadIdx.x == 0 && blockIdx.x == 0) {
        unsigned int w = *(const unsigned int*)probe;
        *flag = (w == 0x3F803F80u) ? 1 : 0;
    }
}

// ---------- counting sort by receiver ----------
__global__ void hist_kernel(const int* __restrict__ receivers, int* __restrict__ counts) {
    int i = blockIdx.x * 256 + threadIdx.x;
    if (i < N_EDGES) atomicAdd(&counts[receivers[i]], 1);
}

__global__ void scan_partial(const int* __restrict__ counts, int* __restrict__ base,
                             int* __restrict__ blockSums) {
    __shared__ int sm[256];
    int b = blockIdx.x, t = threadIdx.x, i = b * 256 + t;
    int v = (i < N_NODES) ? counts[i] : 0;
    sm[t] = v;
    __syncthreads();
    for (int off = 1; off < 256; off <<= 1) {
        int x = (t >= off) ? sm[t - off] : 0;
        __syncthreads();
        sm[t] += x;
        __syncthreads();
    }
    if (i < N_NODES) base[i] = sm[t] - v;  // exclusive
    if (t == 255) blockSums[b] = sm[255];
}

__global__ void scan_tops(int* __restrict__ blockSums, int* __restrict__ tops) {
    __shared__ int sm[256];
    int t = threadIdx.x;
    int v = (t < NBLK_SCAN) ? blockSums[t] : 0;
    sm[t] = v;
    __syncthreads();
    for (int off = 1; off < 256; off <<= 1) {
        int x = (t >= off) ? sm[t - off] : 0;
        __syncthreads();
        sm[t] += x;
        __syncthreads();
    }
    if (t < NBLK_SCAN) tops[t] = sm[t] - v;
}

__global__ void scan_add(int* __restrict__ base, const int* __restrict__ tops,
                         int* __restrict__ cursor) {
    int b = blockIdx.x, i = b * 256 + threadIdx.x;
    if (i < N_NODES) {
        int v = base[i] + tops[b];
        base[i] = v;
        cursor[i] = v;
    }
}

__global__ void scatter_kernel(const int* __restrict__ senders,
                               const int* __restrict__ receivers, int* __restrict__ cursor,
                               int* __restrict__ ss, int* __restrict__ rsrt,
                               int* __restrict__ perm) {
    int i = blockIdx.x * 256 + threadIdx.x;
    if (i < N_EDGES) {
        int r = receivers[i];
        int pos = atomicAdd(&cursor[r], 1);
        ss[pos] = senders[i];
        rsrt[pos] = r;
        perm[pos] = i;
    }
}

// ---------- fused weight prep ----------
// Packed stored-order scheme: every internal 64-wide tensor (h panels, e_lat, n_bf,
// n_lat, recvbuf) stores original column sigma(p)=16*(p&3)+(p>>2) at position p, so
// each lane's 4 acc values are one contiguous b64/b128 write. Consumers are fixed
// here by permuting weight ROWS within each 64-block: slot k -> source row
// (k & ~63) | sigma(k & 63).
struct PrepPtrs {
    const void* W[14];
    const void* eb0;
    const void* nb0;
    const void* glob;
};

#define PREP_WTOTAL 139264
__global__ void prep_all(PrepPtrs p, unsigned short* WbBase, float* b0eff_e, float* b0eff_n,
                         const int* __restrict__ flagp) {
    const int totals[14] = {36864, 12288, 12288, 24576, 12288, 12288, 2048,
                            4096,  4096,  2048,  4096,  4096,  4096,  4096};
    const int ksrc[14] = {192, 64, 64, 128, 64, 64, 7, 64, 64, 4, 64, 64, 64, 64};
    const int sstride[14] = {12416, 4096, 4096, 8320, 4096, 4096, 448,
                             4096,  4096, 256,  4096, 4096, 4096, 4096};
    const int nch[14] = {6, 2, 2, 4, 2, 2, 1, 2, 2, 1, 2, 2, 2, 2};
    // matrices whose INPUT comes from a packed-format tensor -> permute rows.
    // 0=eW0 (e|Ns|Nr all packed), 3=nW0 (n|recv packed), hidden/decoder layers read
    // packed h panels. 6=enW0, 9=eeW0 read RAW inputs.
    const int rowperm[14] = {1, 1, 1, 1, 1, 1, 0, 1, 1, 0, 1, 1, 1, 1};

    const int bf = *flagp;
    int i = blockIdx.x * 256 + threadIdx.x;
    if (i < PREP_WTOTAL) {
        int e = 0, base = 0;
        while (i >= base + totals[e]) { base += totals[e]; e++; }
        int il = i - base;
        int j = il & 7, lane = (il >> 3) & 63, t = (il >> 9) & 3;
        int c = (il >> 11) % nch[e], s = il / (2048 * nch[e]);
        int k = c * 32 + (lane >> 4) * 8 + j;
        int col = t * 16 + (lane & 15);
        int ks = k;
        if (rowperm[e]) {
            int kb = k & 63;
            ks = (k & ~63) | (((kb & 3) << 4) | (kb >> 2));
        }
        WbBase[i] = (k < ksrc[e]) ? f2bf(ldf(p.W[e], (long)s * sstride[e] + (long)ks * 64 + col, bf))
                                  : (unsigned short)0;
    } else if (i < PREP_WTOTAL + 384) {
        int i2 = i - PREP_WTOTAL;
        float g0 = ldf(p.glob, 0, bf), g1 = ldf(p.glob, 1, bf);
        if (i2 < 192) {
            int s = i2 >> 6, col = i2 & 63;
            b0eff_e[i2] = ldf(p.eb0, i2, bf) + g0 * ldf(p.W[0], (long)s * 12416 + 192 * 64 + col, bf)
                                             + g1 * ldf(p.W[0], (long)s * 12416 + 193 * 64 + col, bf);
        } else {
            int il = i2 - 192;
            int s = il >> 6, col = il & 63;
            b0eff_n[il] = ldf(p.nb0, il, bf) + g0 * ldf(p.W[3], (long)s * 8320 + 128 * 64 + col, bf)
                                             + g1 * ldf(p.W[3], (long)s * 8320 + 129 * 64 + col, bf);
        }
    }
}

// ---------- node embedder (MFMA): [R, 7] -> MLP(7,64,64,64); 0 barriers ----------
// Outputs n_lat (f32) and n_bf (bf16) in PACKED stored order (internal format).
template <int DIN, int OUT_BF>
__global__ __launch_bounds__(256) void embed_mfma(
    const void* __restrict__ xin, const unsigned short* __restrict__ Wb0, const void* b0,
    const unsigned short* __restrict__ Wb1, const void* b1,
    const unsigned short* __restrict__ Wb2, const void* b2, void* __restrict__ outp,
    unsigned short* __restrict__ out_bf, const int* __restrict__ perm, int R,
    const int* __restrict__ flagp) {
    __shared__ __align__(16) unsigned short Xs[64 * 40];
    __shared__ __align__(16) unsigned short hbuf[64 * 72];  // per-wave 16-row panels
    const int bf = *flagp;
    const int tid = threadIdx.x;
    const long rb = (long)blockIdx.x * 64;
    const int lane = tid & 63, w = tid >> 6, q = lane >> 4, l15 = lane & 15;
    const int arow = 16 * w + l15, aoff = q * 8;
    unsigned short* hw = hbuf + w * 16 * 72;

    {  // stage own wave's 16 rows
        int r = tid >> 2, seg = tid & 3;
        long idx = rb + r;
        long src = (perm != nullptr && idx < R) ? (long)perm[idx] : idx;
        unsigned short u[8];
#pragma unroll
        for (int j = 0; j < 8; j++) {
            int col = seg * 8 + j;
            u[j] = (col < DIN && idx < R) ? f2bf(ldf(xin, src * DIN + col, bf)) : (unsigned short)0;
        }
        *(uint4*)&Xs[r * 40 + seg * 8] = *(uint4*)u;
    }
    // no barrier: own-wave rows only

    f32x4 acc[4];
    zero4(acc);
    {
        bf16x8 a = *(const bf16x8*)&Xs[arow * 40 + aoff];
        mfma_chunk(acc, a, Wb0 + lane * 8);
        float bb[4];
#pragma unroll
        for (int t = 0; t < 4; t++) bb[t] = ldf(b0, t * 16 + l15, bf);
#pragma unroll
        for (int reg = 0; reg < 4; reg++) {
            uint2 v;
            v.x = cvtpk(gelu_f(acc[0][reg] + bb[0]), gelu_f(acc[1][reg] + bb[1]));
            v.y = cvtpk(gelu_f(acc[2][reg] + bb[2]), gelu_f(acc[3][reg] + bb[3]));
            *(uint2*)&hw[(q * 4 + reg) * 72 + l15 * 4] = v;  // packed panel
        }
    }
    zero4(acc);
    {
#pragma unroll
        for (int c = 0; c < 2; c++) {
            bf16x8 a = *(const bf16x8*)&hw[l15 * 72 + c * 32 + aoff];
            mfma_chunk(acc, a, Wb1 + c * 2048 + lane * 8);
        }
        float bb[4];
#pragma unroll
        for (int t = 0; t < 4; t++) bb[t] = ldf(b1, t * 16 + l15, bf);
#pragma unroll
        for (int reg = 0; reg < 4; reg++) {
            uint2 v;
            v.x = cvtpk(gelu_f(acc[0][reg] + bb[0]), gelu_f(acc[1][reg] + bb[1]));
            v.y = cvtpk(gelu_f(acc[2][reg] + bb[2]), gelu_f(acc[3][reg] + bb[3]));
            *(uint2*)&hw[(q * 4 + reg) * 72 + l15 * 4] = v;
        }
    }
    zero4(acc);
    {
#pragma unroll
        for (int c = 0; c < 2; c++) {
            bf16x8 a = *(const bf16x8*)&hw[l15 * 72 + c * 32 + aoff];
            mfma_chunk(acc, a, Wb2 + c * 2048 + lane * 8);
        }
    }
    float bb[4];
#pragma unroll
    for (int t = 0; t < 4; t++) bb[t] = ldf(b2, t * 16 + l15, bf);
    if (OUT_BF) {
#pragma unroll
        for (int reg = 0; reg < 4; reg++) {
            uint2 v;
            v.x = cvtpk(acc[0][reg] + bb[0], acc[1][reg] + bb[1]);
            v.y = cvtpk(acc[2][reg] + bb[2], acc[3][reg] + bb[3]);
            *(uint2*)&hw[(q * 4 + reg) * 72 + l15 * 4] = v;  // packed
        }
#pragma unroll
        for (int p = 0; p < 2; p++) {
            int r = 16 * w + p * 8 + (lane >> 3), o = lane & 7;
            long idx = rb + r;
            if (idx < R)
                *(uint4*)&((unsigned short*)outp)[idx * 64 + o * 8] =
                    *(const uint4*)&hbuf[r * 72 + o * 8];
        }
    } else {
#pragma unroll
        for (int reg = 0; reg < 4; reg++) {
            long idx = rb + 16 * w + q * 4 + reg;
            if (idx < R) {
                float4 v4 = make_float4(acc[0][reg] + bb[0], acc[1][reg] + bb[1],
                                        acc[2][reg] + bb[2], acc[3][reg] + bb[3]);
                *(float4*)&((float*)outp)[idx * 64 + l15 * 4] = v4;  // packed f32
                uint2 v;
                v.x = cvtpk(v4.x, v4.y);
                v.y = cvtpk(v4.z, v4.w);
                *(uint2*)&out_bf[idx * 64 + l15 * 4] = v;  // packed bf16
            }
        }
    }
}

// ---------- edge step (MFMA + sorted receivers), 1 barrier, 26880 B LDS ----------
// NsNr LDS staging kept: it is the TRANSPOSE that makes the sender/receiver gather
// coalesced (8 consecutive lanes per 128B row). n_bf / e_lat are packed stored-order
// formats; weight rows permuted to match in prep. newe is packed: one float4 write
// per reg; recvbuf lives in stored order. S0: edge embedder fused in.
// LAST: skip residual/LN/e-store.
#define EST 72
#define NST 68
template <int S0, int LAST>
__global__ __launch_bounds__(256) void edge_step(
    unsigned short* __restrict__ e_lat, const unsigned short* __restrict__ n_bf,
    const int* __restrict__ ss, const int* __restrict__ rsrt, const int* __restrict__ perm,
    const void* __restrict__ xe_raw, const unsigned short* __restrict__ We0, const void* eb0_,
    const unsigned short* __restrict__ We1, const void* eb1_,
    const unsigned short* __restrict__ We2, const void* eb2_,
    const unsigned short* __restrict__ Wb0, const unsigned short* __restrict__ Wb1,
    const unsigned short* __restrict__ Wb2, const float* __restrict__ b0eff, const void* b1,
    const void* b2, const void* lnsc, const void* lnbi, float* __restrict__ recvbuf, int s,
    const int* __restrict__ flagp) {
    __shared__ __align__(16) unsigned short Ee[64 * EST];     // 9216 B
    __shared__ __align__(16) unsigned short NsNr[128 * NST];  // 17408 B
    __shared__ int rcvs[64];
    float* newe = (float*)NsNr;  // wave w segment: 16 rows x 68 floats (4352 B)

    const int bf = *flagp;
    const int tid = threadIdx.x;
    const long rb = (long)blockIdx.x * 64;
    const int lane = tid & 63, w = tid >> 6, q = lane >> 4, l15 = lane & 15;
    const int arow = 16 * w + l15, aoff = q * 8;
    unsigned short* hw = Ee + w * 16 * EST;  // wave-private h panel (own e rows)

    // ---- wave-private staging: own 16 rows of Ns / Nr (coalesced 128B rows) ----
#pragma unroll
    for (int p = 0; p < 2; p++) {
        int r = 16 * w + p * 8 + (lane >> 3), o = lane & 7;
        long node = ss[rb + r];
        *(uint4*)&NsNr[r * NST + o * 8] = ((const uint4*)(n_bf + node * 64))[o];
    }
#pragma unroll
    for (int p = 0; p < 2; p++) {
        int r = 16 * w + p * 8 + (lane >> 3), o = lane & 7;
        long node = rsrt[rb + r];
        *(uint4*)&NsNr[(64 + r) * NST + o * 8] = ((const uint4*)(n_bf + node * 64))[o];
    }
    if (lane < 16) rcvs[16 * w + lane] = rsrt[rb + 16 * w + lane];
    // no B1: all reads below touch only own-wave rows

    float ein[4][4];
    f32x4 acc[4];

    if (S0) {
        // ---- inline edge embedder: raw edges [E,4] -> e (ein f32 regs + packed Ee);
        // runs while the NsNr gathers are in flight ----
        zero4(acc);
        {
            bf16x8 a = (bf16x8){0, 0, 0, 0, 0, 0, 0, 0};
            if (q == 0) {
                long src = perm[rb + arow];
                unsigned short u[8] = {0, 0, 0, 0, 0, 0, 0, 0};
#pragma unroll
                for (int j = 0; j < 4; j++) u[j] = f2bf(ldf(xe_raw, src * 4 + j, bf));
                a = *(const bf16x8*)u;
            }
            mfma_chunk(acc, a, We0 + lane * 8);
            float bb[4];
#pragma unroll
            for (int t = 0; t < 4; t++) bb[t] = ldf(eb0_, t * 16 + l15, bf);
#pragma unroll
            for (int reg = 0; reg < 4; reg++) {
                uint2 v;
                v.x = cvtpk(gelu_f(acc[0][reg] + bb[0]), gelu_f(acc[1][reg] + bb[1]));
                v.y = cvtpk(gelu_f(acc[2][reg] + bb[2]), gelu_f(acc[3][reg] + bb[3]));
                *(uint2*)&hw[(q * 4 + reg) * EST + l15 * 4] = v;
            }
        }
        zero4(acc);
        {
#pragma unroll
            for (int c = 0; c < 2; c++) {
                bf16x8 a = *(const bf16x8*)&hw[l15 * EST + c * 32 + aoff];
                mfma_chunk(acc, a, We1 + c * 2048 + lane * 8);
            }
            float bb[4];
#pragma unroll
            for (int t = 0; t < 4; t++) bb[t] = ldf(eb1_, t * 16 + l15, bf);
#pragma unroll
            for (int reg = 0; reg < 4; reg++) {
                uint2 v;
                v.x = cvtpk(gelu_f(acc[0][reg] + bb[0]), gelu_f(acc[1][reg] + bb[1]));
                v.y = cvtpk(gelu_f(acc[2][reg] + bb[2]), gelu_f(acc[3][reg] + bb[3]));
                *(uint2*)&hw[(q * 4 + reg) * EST + l15 * 4] = v;
            }
        }
        zero4(acc);
        {
#pragma unroll
            for (int c = 0; c < 2; c++) {
                bf16x8 a = *(const bf16x8*)&hw[l15 * EST + c * 32 + aoff];
                mfma_chunk(acc, a, We2 + c * 2048 + lane * 8);
            }
            float bb[4];
#pragma unroll
            for (int t = 0; t < 4; t++) bb[t] = ldf(eb2_, t * 16 + l15, bf);
#pragma unroll
            for (int reg = 0; reg < 4; reg++) {
#pragma unroll
                for (int t = 0; t < 4; t++) ein[reg][t] = acc[t][reg] + bb[t];
                uint2 v;
                v.x = cvtpk(ein[reg][0], ein[reg][1]);
                v.y = cvtpk(ein[reg][2], ein[reg][3]);
                *(uint2*)&Ee[(16 * w + q * 4 + reg) * EST + l15 * 4] = v;
            }
        }
    } else {
        // ---- stage own wave's 16 e rows from e_lat (packed format) ----
#pragma unroll
        for (int p = 0; p < 2; p++) {
            int r = 16 * w + p * 8 + (lane >> 3), o = lane & 7;
            *(uint4*)&Ee[r * EST + o * 8] = ((const uint4*)(e_lat + (rb + r) * 64))[o];
        }
        if (!LAST) {  // residual preload: one b64 per row
#pragma unroll
            for (int reg = 0; reg < 4; reg++) {
                uint2 pv = *(const uint2*)&Ee[(16 * w + q * 4 + reg) * EST + l15 * 4];
                ein[reg][0] = __uint_as_float(pv.x << 16);
                ein[reg][1] = __uint_as_float(pv.x & 0xffff0000u);
                ein[reg][2] = __uint_as_float(pv.y << 16);
                ein[reg][3] = __uint_as_float(pv.y & 0xffff0000u);
            }
        }
    }

    zero4(acc);
    {  // layer 0: K=192 from Ee | Ns | Nr (all own-wave rows)
        const unsigned short* B = Wb0 + (long)s * 6 * 2048 + lane * 8;
#pragma unroll
        for (int c = 0; c < 2; c++) {
            bf16x8 a = *(const bf16x8*)&Ee[arow * EST + c * 32 + aoff];
            mfma_chunk(acc, a, B + c * 2048);
        }
#pragma unroll
        for (int c = 0; c < 2; c++) {
            bf16x8 a = *(const bf16x8*)&NsNr[arow * NST + c * 32 + aoff];
            mfma_chunk(acc, a, B + (2 + c) * 2048);
        }
#pragma unroll
        for (int c = 0; c < 2; c++) {
            bf16x8 a = *(const bf16x8*)&NsNr[(64 + arow) * NST + c * 32 + aoff];
            mfma_chunk(acc, a, B + (4 + c) * 2048);
        }
        float bb[4];
#pragma unroll
        for (int t = 0; t < 4; t++) bb[t] = b0eff[s * 64 + t * 16 + l15];
#pragma unroll
        for (int reg = 0; reg < 4; reg++) {
            uint2 v;
            v.x = cvtpk(gelu_f(acc[0][reg] + bb[0]), gelu_f(acc[1][reg] + bb[1]));
            v.y = cvtpk(gelu_f(acc[2][reg] + bb[2]), gelu_f(acc[3][reg] + bb[3]));
            *(uint2*)&hw[(q * 4 + reg) * EST + l15 * 4] = v;
        }
    }
    zero4(acc);
    {  // layer 1 (wave-private h)
        const unsigned short* B = Wb1 + (long)s * 2 * 2048 + lane * 8;
#pragma unroll
        for (int c = 0; c < 2; c++) {
            bf16x8 a = *(const bf16x8*)&hw[l15 * EST + c * 32 + aoff];
            mfma_chunk(acc, a, B + c * 2048);
        }
        float bb[4];
#pragma unroll
        for (int t = 0; t < 4; t++) bb[t] = ldf(b1, (long)s * 64 + t * 16 + l15, bf);
#pragma unroll
        for (int reg = 0; reg < 4; reg++) {
            uint2 v;
            v.x = cvtpk(gelu_f(acc[0][reg] + bb[0]), gelu_f(acc[1][reg] + bb[1]));
            v.y = cvtpk(gelu_f(acc[2][reg] + bb[2]), gelu_f(acc[3][reg] + bb[3]));
            *(uint2*)&hw[(q * 4 + reg) * EST + l15 * 4] = v;
        }
    }
    zero4(acc);
    {  // layer 2
        const unsigned short* B = Wb2 + (long)s * 2 * 2048 + lane * 8;
#pragma unroll
        for (int c = 0; c < 2; c++) {
            bf16x8 a = *(const bf16x8*)&hw[l15 * EST + c * 32 + aoff];
            mfma_chunk(acc, a, B + c * 2048);
        }
    }
    __syncthreads();  // B2: all layer-0 NsNr reads drained before newe overlay

    // ---- fin = new_e + b2 (bias load overlaps layer-2 chain); packed newe ----
    float fin[4][4];
    {
        float bb[4];
#pragma unroll
        for (int t = 0; t < 4; t++) bb[t] = ldf(b2, (long)s * 64 + t * 16 + l15, bf);
#pragma unroll
        for (int reg = 0; reg < 4; reg++)
#pragma unroll
            for (int t = 0; t < 4; t++) fin[reg][t] = acc[t][reg] + bb[t];
    }
    float lsc[4], lbi[4];
    if (!LAST) {
#pragma unroll
        for (int t = 0; t < 4; t++) {
            lsc[t] = ldf(lnsc, (long)s * 64 + t * 16 + l15, bf);
            lbi[t] = ldf(lnbi, (long)s * 64 + t * 16 + l15, bf);
        }
    }
#pragma unroll
    for (int reg = 0; reg < 4; reg++) {
        const int lr = q * 4 + reg;
        // packed stored-order newe row: one b128 instead of 16 b32
        *(float4*)&newe[w * 1088 + lr * 68 + l15 * 4] =
            make_float4(fin[reg][0], fin[reg][1], fin[reg][2], fin[reg][3]);
        if (!LAST) {
            float u[4], ssum = 0.f;
#pragma unroll
            for (int t = 0; t < 4; t++) {
                u[t] = ein[reg][t] + fin[reg][t];
                ssum += u[t];
            }
#pragma unroll
            for (int m = 1; m < 16; m <<= 1) ssum += __shfl_xor(ssum, m, 64);
            const float mu = ssum * (1.0f / 64.0f);
            float d[4], vv = 0.f;
#pragma unroll
            for (int t = 0; t < 4; t++) { d[t] = u[t] - mu; vv += d[t] * d[t]; }
#pragma unroll
            for (int m = 1; m < 16; m <<= 1) vv += __shfl_xor(vv, m, 64);
            const float rs = rsqrtf(vv * (1.0f / 64.0f) + 1e-6f);
            uint2 v;
            v.x = cvtpk(d[0] * rs * lsc[0] + lbi[0], d[1] * rs * lsc[1] + lbi[1]);
            v.y = cvtpk(d[2] * rs * lsc[2] + lbi[2], d[3] * rs * lsc[3] + lbi[3]);
            *(uint2*)&Ee[(16 * w + lr) * EST + l15 * 4] = v;  // packed LN'd e
        }
    }
    // no B3: e-store reads only own-wave Ee rows

    if (!LAST) {  // wave-private vectorized e store (packed format)
#pragma unroll
        for (int p = 0; p < 2; p++) {
            int r = 16 * w + p * 8 + (lane >> 3), o = lane & 7;
            *(uint4*)&e_lat[(rb + r) * 64 + o * 8] = *(const uint4*)&Ee[r * EST + o * 8];
        }
    }
    // ---- run-segmented scatter-add (sorted receivers; recvbuf in stored order) ----
    {
        const int col = tid & 63, g = tid >> 6;
        float a = 0.f;
#pragma unroll
        for (int rr = 0; rr < 16; rr++) {
            const int r = 16 * g + rr;
            a += newe[g * 1088 + rr * 68 + col];
            if (rr == 15 || rcvs[r + 1] != rcvs[r]) {  // wave-uniform branch
                atomicAdd(&recvbuf[(long)rcvs[r] * 64 + col], a);
                a = 0.f;
            }
        }
    }
}

// ---------- node update (MFMA), 0 barriers; FINAL fuses the decoder ----------
#define NXS 136
template <int FINAL>
__global__ __launch_bounds__(256) void node_update_mfma(
    float* __restrict__ n_lat, unsigned short* __restrict__ n_bf, float* __restrict__ recvbuf,
    const unsigned short* __restrict__ Wb0, const float* __restrict__ b0eff,
    const unsigned short* __restrict__ Wb1, const void* b1,
    const unsigned short* __restrict__ Wb2, const void* b2, const void* lnsc,
    const void* lnbi, const unsigned short* __restrict__ WbD0, const void* db0,
    const unsigned short* __restrict__ WbD1, const void* db1, const void* dW2,
    const void* db2, void* __restrict__ outp, int s, const int* __restrict__ flagp) {
    __shared__ __align__(16) unsigned short Xs[64 * NXS];   // 17408 B
    __shared__ __align__(16) unsigned short hbuf[64 * 72];  // per-wave panels
    const int bf = *flagp;
    const int tid = threadIdx.x;
    const long rb = (long)blockIdx.x * 64;
    const int lane = tid & 63, w = tid >> 6, q = lane >> 4, l15 = lane & 15;
    const int arow = 16 * w + l15, aoff = q * 8;
    unsigned short* hw = hbuf + w * 16 * 72;

#pragma unroll
    for (int p = 0; p < 2; p++) {
        int r = 16 * w + p * 8 + (lane >> 3), o = lane & 7;
        long idx = rb + r;
        uint4 v = {0u, 0u, 0u, 0u};
        if (idx < N_NODES) v = ((const uint4*)(n_bf + idx * 64))[o];
        *(uint4*)&Xs[r * NXS + o * 8] = v;
    }
#pragma unroll
    for (int p = 0; p < 2; p++) {
        int r = 16 * w + p * 8 + (lane >> 3), o = lane & 7;
        long idx = rb + r;
        uint4 v = {0u, 0u, 0u, 0u};
        if (idx < N_NODES) {
            const float* src = recvbuf + idx * 64 + o * 8;
            float4 x0 = *(const float4*)src, x1 = *(const float4*)(src + 4);
            v.x = cvtpk(x0.x, x0.y);
            v.y = cvtpk(x0.z, x0.w);
            v.z = cvtpk(x1.x, x1.y);
            v.w = cvtpk(x1.z, x1.w);
        }
        *(uint4*)&Xs[r * NXS + 64 + o * 8] = v;
    }
    // no barrier: own-wave rows only

    f32x4 acc[4];
    zero4(acc);
    {  // layer 0: K=128 (glob folded into b0eff)
        const unsigned short* B = Wb0 + (long)s * 4 * 2048 + lane * 8;
#pragma unroll
        for (int c = 0; c < 4; c++) {
            bf16x8 a = *(const bf16x8*)&Xs[arow * NXS + c * 32 + aoff];
            mfma_chunk(acc, a, B + c * 2048);
        }
        float bb[4];
#pragma unroll
        for (int t = 0; t < 4; t++) bb[t] = b0eff[s * 64 + t * 16 + l15];
#pragma unroll
        for (int reg = 0; reg < 4; reg++) {
            uint2 v;
            v.x = cvtpk(gelu_f(acc[0][reg] + bb[0]), gelu_f(acc[1][reg] + bb[1]));
            v.y = cvtpk(gelu_f(acc[2][reg] + bb[2]), gelu_f(acc[3][reg] + bb[3]));
            *(uint2*)&hw[(q * 4 + reg) * 72 + l15 * 4] = v;
        }
    }
    zero4(acc);
    {
        const unsigned short* B = Wb1 + (long)s * 2 * 2048 + lane * 8;
#pragma unroll
        for (int c = 0; c < 2; c++) {
            bf16x8 a = *(const bf16x8*)&hw[l15 * 72 + c * 32 + aoff];
            mfma_chunk(acc, a, B + c * 2048);
        }
        float bb[4];
#pragma unroll
        for (int t = 0; t < 4; t++) bb[t] = ldf(b1, (long)s * 64 + t * 16 + l15, bf);
#pragma unroll
        for (int reg = 0; reg < 4; reg++) {
            uint2 v;
            v.x = cvtpk(gelu_f(acc[0][reg] + bb[0]), gelu_f(acc[1][reg] + bb[1]));
            v.y = cvtpk(gelu_f(acc[2][reg] + bb[2]), gelu_f(acc[3][reg] + bb[3]));
            *(uint2*)&hw[(q * 4 + reg) * 72 + l15 * 4] = v;
        }
    }
    zero4(acc);
    {
        const unsigned short* B = Wb2 + (long)s * 2 * 2048 + lane * 8;
#pragma unroll
        for (int c = 0; c < 2; c++) {
            bf16x8 a = *(const bf16x8*)&hw[l15 * 72 + c * 32 + aoff];
            mfma_chunk(acc, a, B + c * 2048);
        }
    }
    float b2v[4], lsc[4], lbi[4];
#pragma unroll
    for (int t = 0; t < 4; t++) {
        b2v[t] = ldf(b2, (long)s * 64 + t * 16 + l15, bf);
        lsc[t] = ldf(lnsc, (long)s * 64 + t * 16 + l15, bf);
        lbi[t] = ldf(lnbi, (long)s * 64 + t * 16 + l15, bf);
    }
#pragma unroll
    for (int reg = 0; reg < 4; reg++) {
        const int rowl = 16 * w + q * 4 + reg;
        const long idx = rb + rowl;
        const bool valid = idx < N_NODES;
        float4 xn4 = make_float4(0.f, 0.f, 0.f, 0.f);
        if (valid) xn4 = *(const float4*)&n_lat[idx * 64 + l15 * 4];  // packed f32
        float u[4], ssum = 0.f;
        u[0] = xn4.x + acc[0][reg] + b2v[0];
        u[1] = xn4.y + acc[1][reg] + b2v[1];
        u[2] = xn4.z + acc[2][reg] + b2v[2];
        u[3] = xn4.w + acc[3][reg] + b2v[3];
#pragma unroll
        for (int t = 0; t < 4; t++) ssum += u[t];
#pragma unroll
        for (int m = 1; m < 16; m <<= 1) ssum += __shfl_xor(ssum, m, 64);
        const float mu = ssum * (1.0f / 64.0f);
        float d[4], vv = 0.f;
#pragma unroll
        for (int t = 0; t < 4; t++) { d[t] = u[t] - mu; vv += d[t] * d[t]; }
#pragma unroll
        for (int m = 1; m < 16; m <<= 1) vv += __shfl_xor(vv, m, 64);
        const float rs = rsqrtf(vv * (1.0f / 64.0f) + 1e-6f);
        if (FINAL) {
            // n is consumed only by the decoder -> packed panel, no global n stores
            uint2 v;
            v.x = cvtpk(d[0] * rs * lsc[0] + lbi[0], d[1] * rs * lsc[1] + lbi[1]);
            v.y = cvtpk(d[2] * rs * lsc[2] + lbi[2], d[3] * rs * lsc[3] + lbi[3]);
            *(uint2*)&hw[(q * 4 + reg) * 72 + l15 * 4] = v;
        } else if (valid) {
            float4 v4 = make_float4(d[0] * rs * lsc[0] + lbi[0], d[1] * rs * lsc[1] + lbi[1],
                                    d[2] * rs * lsc[2] + lbi[2], d[3] * rs * lsc[3] + lbi[3]);
            *(float4*)&n_lat[idx * 64 + l15 * 4] = v4;  // packed f32
            uint2 v;
            v.x = cvtpk(v4.x, v4.y);
            v.y = cvtpk(v4.z, v4.w);
            *(uint2*)&n_bf[idx * 64 + l15 * 4] = v;  // packed bf16
            *(float4*)&recvbuf[idx * 64 + l15 * 4] = make_float4(0.f, 0.f, 0.f, 0.f);
        }
    }
    if (FINAL) {  // ---- fused decoder: MLP(64,64,64,3) on the packed LN panel ----
        zero4(acc);
        {
#pragma unroll
            for (int c = 0; c < 2; c++) {
                bf16x8 a = *(const bf16x8*)&hw[l15 * 72 + c * 32 + aoff];
                mfma_chunk(acc, a, WbD0 + c * 2048 + lane * 8);
            }
            float bb[4];
#pragma unroll
            for (int t = 0; t < 4; t++) bb[t] = ldf(db0, t * 16 + l15, bf);
#pragma unroll
            for (int reg = 0; reg < 4; reg++) {
                uint2 v;
                v.x = cvtpk(gelu_f(acc[0][reg] + bb[0]), gelu_f(acc[1][reg] + bb[1]));
                v.y = cvtpk(gelu_f(acc[2][reg] + bb[2]), gelu_f(acc[3][reg] + bb[3]));
                *(uint2*)&hw[(q * 4 + reg) * 72 + l15 * 4] = v;
            }
        }
        zero4(acc);
        {
#pragma unroll
            for (int c = 0; c < 2; c++) {
                bf16x8 a = *(const bf16x8*)&hw[l15 * 72 + c * 32 + aoff];
                mfma_chunk(acc, a, WbD1 + c * 2048 + lane * 8);
            }
            float bb[4];
#pragma unroll
            for (int t = 0; t < 4; t++) bb[t] = ldf(db1, t * 16 + l15, bf);
#pragma unroll
            for (int reg = 0; reg < 4; reg++) {
                uint2 v;
                v.x = cvtpk(gelu_f(acc[0][reg] + bb[0]), gelu_f(acc[1][reg] + bb[1]));
                v.y = cvtpk(gelu_f(acc[2][reg] + bb[2]), gelu_f(acc[3][reg] + bb[3]));
                *(uint2*)&hw[(q * 4 + reg) * 72 + l15 * 4] = v;
            }
        }
        const int col = tid & 63;
        const int r0 = w * 16;
        if (col < 3) {
            float a[16];
            const float b = ldf(db2, col, bf);
#pragma unroll
            for (int i = 0; i < 16; i++) a[i] = b;
            for (int k = 0; k < 64; k++) {
                // hw position k holds original feature sigma(k) = 16*(k&3)+(k>>2)
                const int ksrc2 = ((k & 3) << 4) | (k >> 2);
                float wv = ldf(dW2, (long)ksrc2 * 3 + col, bf);
#pragma unroll
                for (int i = 0; i < 16; i++) a[i] = fmaf(bf2f(hw[i * 72 + k]), wv, a[i]);
            }
            for (int i = 0; i < 16; i++) {
                const long idx = rb + r0 + i;
                if (idx < N_NODES) {
                    if (bf)
                        ((unsigned short*)outp)[idx * 3 + col] = f2bf(a[i]);
                    else
                        ((float*)outp)[idx * 3 + col] = a[i];
                }
            }
        }
    }
}

// ---------- launch ----------
extern "C" void kernel_launch(void* const* d_in, const int* in_sizes, int n_in, void* d_out,
                              int out_size, void* d_ws, size_t ws_size, hipStream_t stream) {
    const void* nodes = d_in[0];
    const void* edges = d_in[1];
    const void* glob = d_in[2];
    const void *enW0 = d_in[3], *enb0 = d_in[4], *enW1 = d_in[5], *enb1 = d_in[6],
               *enW2 = d_in[7], *enb2 = d_in[8];
    const void *eeW0 = d_in[9], *eeb0 = d_in[10], *eeW1 = d_in[11], *eeb1 = d_in[12],
               *eeW2 = d_in[13], *eeb2 = d_in[14];
    const void *eW0 = d_in[15], *eb0 = d_in[16], *eW1 = d_in[17], *eb1 = d_in[18],
               *eW2 = d_in[19], *eb2 = d_in[20];
    const void *nW0 = d_in[21], *nb0 = d_in[22], *nW1 = d_in[23], *nb1 = d_in[24],
               *nW2 = d_in[25], *nb2 = d_in[26];
    const void *lnns = d_in[27], *lnnb = d_in[28], *lnes = d_in[29], *lneb = d_in[30];
    const void *dW0 = d_in[31], *db0 = d_in[32], *dW1 = d_in[33], *db1 = d_in[34],
               *dW2 = d_in[35], *db2 = d_in[36];
    const int* senders = (const int*)d_in[37];
    const int* receivers = (const int*)d_in[38];

    // workspace layout
    float* n_lat = (float*)d_ws;               // 3,200,000 f32
    float* recvb = n_lat + 3200000;            // 3,200,000 f32
    float* b0eff_e = recvb + 3200000;          // 192
    float* b0eff_n = b0eff_e + 192;            // 192
    int* flag = (int*)(b0eff_n + 192);         // pad to 64 f32
    unsigned short* e_lat = (unsigned short*)(b0eff_n + 256);  // 51,200,000 bf16
    unsigned short* n_bf = e_lat + 51200000;   // 3,200,000 bf16
    unsigned short* WbBase = n_bf + 3200000;   // 139,264 bf16
    unsigned short* WbE0 = WbBase;
    unsigned short* WbE1 = WbBase + 36864;
    unsigned short* WbE2 = WbBase + 49152;
    unsigned short* WbN0 = WbBase + 61440;
    unsigned short* WbN1 = WbBase + 86016;
    unsigned short* WbN2 = WbBase + 98304;
    unsigned short* WbNE0 = WbBase + 110592;
    unsigned short* WbNE1 = WbBase + 112640;
    unsigned short* WbNE2 = WbBase + 116736;
    unsigned short* WbEE0 = WbBase + 120832;
    unsigned short* WbEE1 = WbBase + 122880;
    unsigned short* WbEE2 = WbBase + 126976;
    unsigned short* WbD0 = WbBase + 131072;
    unsigned short* WbD1 = WbBase + 135168;
    int* counts = (int*)(WbBase + 139264 + 64);  // aligned scratch
    int* sbase = counts + N_NODES;
    int* cursor = sbase + N_NODES;
    int* blockSums = cursor + N_NODES;  // 256
    int* tops = blockSums + 256;        // 256
    int* ss = tops + 256;               // N_EDGES
    int* rsrt = ss + N_EDGES;           // N_EDGES
    int* perm = rsrt + N_EDGES;         // N_EDGES

    detect_kernel<<<1, 64, 0, stream>>>(lnns, flag);

    PrepPtrs pp;
    pp.W[0] = eW0;  pp.W[1] = eW1;  pp.W[2] = eW2;
    pp.W[3] = nW0;  pp.W[4] = nW1;  pp.W[5] = nW2;
    pp.W[6] = enW0; pp.W[7] = enW1; pp.W[8] = enW2;
    pp.W[9] = eeW0; pp.W[10] = eeW1; pp.W[11] = eeW2;
    pp.W[12] = dW0; pp.W[13] = dW1;
    pp.eb0 = eb0; pp.nb0 = nb0; pp.glob = glob;
    prep_all<<<(PREP_WTOTAL + 384 + 255) / 256, 256, 0, stream>>>(pp, WbBase, b0eff_e, b0eff_n,
                                                                  flag);
    hipMemsetAsync(recvb, 0, (size_t)N_NODES * 64 * sizeof(float), stream);
    hipMemsetAsync(counts, 0, (size_t)N_NODES * sizeof(int), stream);

    // counting sort of edges by receiver
    hist_kernel<<<(N_EDGES + 255) / 256, 256, 0, stream>>>(receivers, counts);
    scan_partial<<<NBLK_SCAN, 256, 0, stream>>>(counts, sbase, blockSums);
    scan_tops<<<1, 256, 0, stream>>>(blockSums, tops);
    scan_add<<<NBLK_SCAN, 256, 0, stream>>>(sbase, tops, cursor);
    scatter_kernel<<<(N_EDGES + 255) / 256, 256, 0, stream>>>(senders, receivers, cursor, ss,
                                                              rsrt, perm);

    embed_mfma<7, 0><<<(N_NODES + 63) / 64, 256, 0, stream>>>(
        nodes, WbNE0, enb0, WbNE1, enb1, WbNE2, enb2, n_lat, n_bf, (const int*)nullptr,
        N_NODES, flag);

    // step 0: edge embedder fused into the edge update (no e_lat read, residual in f32)
    edge_step<1, 0><<<N_EDGES / 64, 256, 0, stream>>>(
        e_lat, n_bf, ss, rsrt, perm, edges, WbEE0, eeb0, WbEE1, eeb1, WbEE2, eeb2,
        WbE0, WbE1, WbE2, b0eff_e, eb1, eb2, lnes, lneb, recvb, 0, flag);
    node_update_mfma<0><<<(N_NODES + 63) / 64, 256, 0, stream>>>(
        n_lat, n_bf, recvb, WbN0, b0eff_n, WbN1, nb1, WbN2, nb2, lnns, lnnb,
        nullptr, nullptr, nullptr, nullptr, nullptr, nullptr, nullptr, 0, flag);

    edge_step<0, 0><<<N_EDGES / 64, 256, 0, stream>>>(
        e_lat, n_bf, ss, rsrt, perm, edges, WbEE0, eeb0, WbEE1, eeb1, WbEE2, eeb2,
        WbE0, WbE1, WbE2, b0eff_e, eb1, eb2, lnes, lneb, recvb, 1, flag);
    node_update_mfma<0><<<(N_NODES + 63) / 64, 256, 0, stream>>>(
        n_lat, n_bf, recvb, WbN0, b0eff_n, WbN1, nb1, WbN2, nb2, lnns, lnnb,
        nullptr, nullptr, nullptr, nullptr, nullptr, nullptr, nullptr, 1, flag);

    // step 2: e is dead after this step -> no LN/e-store; decoder fused into node update
    edge_step<0, 1><<<N_EDGES / 64, 256, 0, stream>>>(
        e_lat, n_bf, ss, rsrt, perm, edges, WbEE0, eeb0, WbEE1, eeb1, WbEE2, eeb2,
        WbE0, WbE1, WbE2, b0eff_e, eb1, eb2, lnes, lneb, recvb, 2, flag);
    node_update_mfma<1><<<(N_NODES + 63) / 64, 256, 0, stream>>>(
        n_lat, n_bf, recvb, WbN0, b0eff_n, WbN1, nb1, WbN2, nb2, lnns, lnnb,
        WbD0, db0, WbD1, db1, dW2, db2, d_out, 2, flag);
}

// Round 9
// 657.603 us; speedup vs baseline: 1.0480x; 1.0141x over previous
//
#include <hip/hip_runtime.h>

#define N_NODES 50000
#define N_EDGES 800000
#define NSTEPS 3
#define NBLK_SCAN 196  // ceil(50000/256)

typedef __attribute__((ext_vector_type(8))) short bf16x8;
typedef __attribute__((ext_vector_type(4))) float f32x4;

// ---------- helpers ----------

__device__ __forceinline__ float ldf(const void* p, long i, int bf) {
    if (bf) {
        unsigned int u = ((const unsigned short*)p)[i];
        u <<= 16;
        return __uint_as_float(u);
    }
    return ((const float*)p)[i];
}

// round-half-up bf16 (2 VALU ops; differs from RNE only at exact ties)
__device__ __forceinline__ unsigned short f2bf(float f) {
    return (unsigned short)((__float_as_uint(f) + 0x8000u) >> 16);
}

__device__ __forceinline__ float bf2f(unsigned short u) {
    return __uint_as_float(((unsigned int)u) << 16);
}

// packed f32x2 -> bf16x2 (RNE), single VALU op
__device__ __forceinline__ unsigned int cvtpk(float a, float b) {
    unsigned int r;
    asm("v_cvt_pk_bf16_f32 %0, %1, %2" : "=v"(r) : "v"(a), "v"(b));
    return r;
}

// jax.nn.gelu tanh-approx via sigmoid identity: 0.5x(1+tanh(z)) = x*sigmoid(2z)
__device__ __forceinline__ float gelu_f(float x) {
    float x2 = x * x;
    float m = x * fmaf(-0.10294325f, x2, -2.30220847f);
    float e = __builtin_amdgcn_exp2f(m);
    return x * __builtin_amdgcn_rcpf(1.0f + e);
}

// SCHEDULING LEDGER (tried, regressed -- do not retry):
// 1. bias-in-accumulator (MFMA C preload): +23us -- moves bias load to layer head,
//    first MFMA stalls on L2 latency (r5).
// 2. explicit B-fragment double-buffering via named regs (bfrag/loadB): +18us --
//    VGPR 48->56, achieved occupancy 52.8->42.6%; 6 waves/SIMD of TLP already
//    covers the L2-hot weight-load latency, forced live ranges only cost occupancy (r7).
// The compiler's minimal-register schedule at VGPR=48 is the local optimum.
__device__ __forceinline__ void zero4(f32x4 a[4]) {
#pragma unroll
    for (int t = 0; t < 4; t++) a[t] = (f32x4){0.f, 0.f, 0.f, 0.f};
}

__device__ __forceinline__ void mfma_chunk(f32x4 acc[4], bf16x8 a, const unsigned short* bb) {
    acc[0] = __builtin_amdgcn_mfma_f32_16x16x32_bf16(a, *(const bf16x8*)(bb + 0), acc[0], 0, 0, 0);
    acc[1] = __builtin_amdgcn_mfma_f32_16x16x32_bf16(a, *(const bf16x8*)(bb + 512), acc[1], 0, 0, 0);
    acc[2] = __builtin_amdgcn_mfma_f32_16x16x32_bf16(a, *(const bf16x8*)(bb + 1024), acc[2], 0, 0, 0);
    acc[3] = __builtin_amdgcn_mfma_f32_16x16x32_bf16(a, *(const bf16x8*)(bb + 1536), acc[3], 0, 0, 0);
}

// ---------- dtype detect ----------
__global__ void detect_kernel(const void* probe, int* flag) {
    if (threadIdx.x == 0 && blockIdx.x == 0) {
        unsigned int w = *(const unsigned int*)probe;
        *flag = (w == 0x3F803F80u) ? 1 : 0;
    }
}

// ---------- counting sort by receiver ----------
__global__ void hist_kernel(const int* __restrict__ receivers, int* __restrict__ counts) {
    int i = blockIdx.x * 256 + threadIdx.x;
    if (i < N_EDGES) atomicAdd(&counts[receivers[i]], 1);
}

__global__ void scan_partial(const int* __restrict__ counts, int* __restrict__ base,
                             int* __restrict__ blockSums) {
    __shared__ int sm[256];
    int b = blockIdx.x, t = threadIdx.x, i = b * 256 + t;
    int v = (i < N_NODES) ? counts[i] : 0;
    sm[t] = v;
    __syncthreads();
    for (int off = 1; off < 256; off <<= 1) {
        int x = (t >= off) ? sm[t - off] : 0;
        __syncthreads();
        sm[t] += x;
        __syncthreads();
    }
    if (i < N_NODES) base[i] = sm[t] - v;  // exclusive
    if (t == 255) blockSums[b] = sm[255];
}

__global__ void scan_tops(int* __restrict__ blockSums, int* __restrict__ tops) {
    __shared__ int sm[256];
    int t = threadIdx.x;
    int v = (t < NBLK_SCAN) ? blockSums[t] : 0;
    sm[t] = v;
    __syncthreads();
    for (int off = 1; off < 256; off <<= 1) {
        int x = (t >= off) ? sm[t - off] : 0;
        __syncthreads();
        sm[t] += x;
        __syncthreads();
    }
    if (t < NBLK_SCAN) tops[t] = sm[t] - v;
}

__global__ void scan_add(int* __restrict__ base, const int* __restrict__ tops,
                         int* __restrict__ cursor) {
    int b = blockIdx.x, i = b * 256 + threadIdx.x;
    if (i < N_NODES) {
        int v = base[i] + tops[b];
        base[i] = v;
        cursor[i] = v;
    }
}

__global__ void scatter_kernel(const int* __restrict__ senders,
                               const int* __restrict__ receivers, int* __restrict__ cursor,
                               int* __restrict__ ss, int* __restrict__ rsrt,
                               int* __restrict__ perm) {
    int i = blockIdx.x * 256 + threadIdx.x;
    if (i < N_EDGES) {
        int r = receivers[i];
        int pos = atomicAdd(&cursor[r], 1);
        ss[pos] = senders[i];
        rsrt[pos] = r;
        perm[pos] = i;
    }
}

// ---------- fused weight prep ----------
// Packed stored-order scheme: every internal 64-wide tensor (h panels, e_lat, n_bf,
// n_lat, recvbuf) stores original column sigma(p)=16*(p&3)+(p>>2) at position p, so
// each lane's 4 acc values are one contiguous b64/b128 write. Consumers are fixed
// here by permuting weight ROWS within each 64-block: slot k -> source row
// (k & ~63) | sigma(k & 63).
struct PrepPtrs {
    const void* W[14];
    const void* eb0;
    const void* nb0;
    const void* glob;
};

#define PREP_WTOTAL 139264
__global__ void prep_all(PrepPtrs p, unsigned short* WbBase, float* b0eff_e, float* b0eff_n,
                         const int* __restrict__ flagp) {
    const int totals[14] = {36864, 12288, 12288, 24576, 12288, 12288, 2048,
                            4096,  4096,  2048,  4096,  4096,  4096,  4096};
    const int ksrc[14] = {192, 64, 64, 128, 64, 64, 7, 64, 64, 4, 64, 64, 64, 64};
    const int sstride[14] = {12416, 4096, 4096, 8320, 4096, 4096, 448,
                             4096,  4096, 256,  4096, 4096, 4096, 4096};
    const int nch[14] = {6, 2, 2, 4, 2, 2, 1, 2, 2, 1, 2, 2, 2, 2};
    // matrices whose INPUT comes from a packed-format tensor -> permute rows.
    // 0=eW0 (e|Ns|Nr all packed), 3=nW0 (n|recv packed), hidden/decoder layers read
    // packed h panels. 6=enW0, 9=eeW0 read RAW inputs.
    const int rowperm[14] = {1, 1, 1, 1, 1, 1, 0, 1, 1, 0, 1, 1, 1, 1};

    const int bf = *flagp;
    int i = blockIdx.x * 256 + threadIdx.x;
    if (i < PREP_WTOTAL) {
        int e = 0, base = 0;
        while (i >= base + totals[e]) { base += totals[e]; e++; }
        int il = i - base;
        int j = il & 7, lane = (il >> 3) & 63, t = (il >> 9) & 3;
        int c = (il >> 11) % nch[e], s = il / (2048 * nch[e]);
        int k = c * 32 + (lane >> 4) * 8 + j;
        int col = t * 16 + (lane & 15);
        int ks = k;
        if (rowperm[e]) {
            int kb = k & 63;
            ks = (k & ~63) | (((kb & 3) << 4) | (kb >> 2));
        }
        WbBase[i] = (k < ksrc[e]) ? f2bf(ldf(p.W[e], (long)s * sstride[e] + (long)ks * 64 + col, bf))
                                  : (unsigned short)0;
    } else if (i < PREP_WTOTAL + 384) {
        int i2 = i - PREP_WTOTAL;
        float g0 = ldf(p.glob, 0, bf), g1 = ldf(p.glob, 1, bf);
        if (i2 < 192) {
            int s = i2 >> 6, col = i2 & 63;
            b0eff_e[i2] = ldf(p.eb0, i2, bf) + g0 * ldf(p.W[0], (long)s * 12416 + 192 * 64 + col, bf)
                                             + g1 * ldf(p.W[0], (long)s * 12416 + 193 * 64 + col, bf);
        } else {
            int il = i2 - 192;
            int s = il >> 6, col = il & 63;
            b0eff_n[il] = ldf(p.nb0, il, bf) + g0 * ldf(p.W[3], (long)s * 8320 + 128 * 64 + col, bf)
                                             + g1 * ldf(p.W[3], (long)s * 8320 + 129 * 64 + col, bf);
        }
    }
}

// ---------- node embedder (MFMA): [R, 7] -> MLP(7,64,64,64); 0 barriers ----------
// Outputs n_lat (f32) and n_bf (bf16) in PACKED stored order (internal format).
template <int DIN, int OUT_BF>
__global__ __launch_bounds__(256) void embed_mfma(
    const void* __restrict__ xin, const unsigned short* __restrict__ Wb0, const void* b0,
    const unsigned short* __restrict__ Wb1, const void* b1,
    const unsigned short* __restrict__ Wb2, const void* b2, void* __restrict__ outp,
    unsigned short* __restrict__ out_bf, const int* __restrict__ perm, int R,
    const int* __restrict__ flagp) {
    __shared__ __align__(16) unsigned short Xs[64 * 40];
    __shared__ __align__(16) unsigned short hbuf[64 * 72];  // per-wave 16-row panels
    const int bf = *flagp;
    const int tid = threadIdx.x;
    const long rb = (long)blockIdx.x * 64;
    const int lane = tid & 63, w = tid >> 6, q = lane >> 4, l15 = lane & 15;
    const int arow = 16 * w + l15, aoff = q * 8;
    unsigned short* hw = hbuf + w * 16 * 72;

    {  // stage own wave's 16 rows
        int r = tid >> 2, seg = tid & 3;
        long idx = rb + r;
        long src = (perm != nullptr && idx < R) ? (long)perm[idx] : idx;
        unsigned short u[8];
#pragma unroll
        for (int j = 0; j < 8; j++) {
            int col = seg * 8 + j;
            u[j] = (col < DIN && idx < R) ? f2bf(ldf(xin, src * DIN + col, bf)) : (unsigned short)0;
        }
        *(uint4*)&Xs[r * 40 + seg * 8] = *(uint4*)u;
    }
    // no barrier: own-wave rows only

    f32x4 acc[4];
    zero4(acc);
    {
        bf16x8 a = *(const bf16x8*)&Xs[arow * 40 + aoff];
        mfma_chunk(acc, a, Wb0 + lane * 8);
        float bb[4];
#pragma unroll
        for (int t = 0; t < 4; t++) bb[t] = ldf(b0, t * 16 + l15, bf);
#pragma unroll
        for (int reg = 0; reg < 4; reg++) {
            uint2 v;
            v.x = cvtpk(gelu_f(acc[0][reg] + bb[0]), gelu_f(acc[1][reg] + bb[1]));
            v.y = cvtpk(gelu_f(acc[2][reg] + bb[2]), gelu_f(acc[3][reg] + bb[3]));
            *(uint2*)&hw[(q * 4 + reg) * 72 + l15 * 4] = v;  // packed panel
        }
    }
    zero4(acc);
    {
#pragma unroll
        for (int c = 0; c < 2; c++) {
            bf16x8 a = *(const bf16x8*)&hw[l15 * 72 + c * 32 + aoff];
            mfma_chunk(acc, a, Wb1 + c * 2048 + lane * 8);
        }
        float bb[4];
#pragma unroll
        for (int t = 0; t < 4; t++) bb[t] = ldf(b1, t * 16 + l15, bf);
#pragma unroll
        for (int reg = 0; reg < 4; reg++) {
            uint2 v;
            v.x = cvtpk(gelu_f(acc[0][reg] + bb[0]), gelu_f(acc[1][reg] + bb[1]));
            v.y = cvtpk(gelu_f(acc[2][reg] + bb[2]), gelu_f(acc[3][reg] + bb[3]));
            *(uint2*)&hw[(q * 4 + reg) * 72 + l15 * 4] = v;
        }
    }
    zero4(acc);
    {
#pragma unroll
        for (int c = 0; c < 2; c++) {
            bf16x8 a = *(const bf16x8*)&hw[l15 * 72 + c * 32 + aoff];
            mfma_chunk(acc, a, Wb2 + c * 2048 + lane * 8);
        }
    }
    float bb[4];
#pragma unroll
    for (int t = 0; t < 4; t++) bb[t] = ldf(b2, t * 16 + l15, bf);
    if (OUT_BF) {
#pragma unroll
        for (int reg = 0; reg < 4; reg++) {
            uint2 v;
            v.x = cvtpk(acc[0][reg] + bb[0], acc[1][reg] + bb[1]);
            v.y = cvtpk(acc[2][reg] + bb[2], acc[3][reg] + bb[3]);
            *(uint2*)&hw[(q * 4 + reg) * 72 + l15 * 4] = v;  // packed
        }
#pragma unroll
        for (int p = 0; p < 2; p++) {
            int r = 16 * w + p * 8 + (lane >> 3), o = lane & 7;
            long idx = rb + r;
            if (idx < R)
                *(uint4*)&((unsigned short*)outp)[idx * 64 + o * 8] =
                    *(const uint4*)&hbuf[r * 72 + o * 8];
        }
    } else {
#pragma unroll
        for (int reg = 0; reg < 4; reg++) {
            long idx = rb + 16 * w + q * 4 + reg;
            if (idx < R) {
                float4 v4 = make_float4(acc[0][reg] + bb[0], acc[1][reg] + bb[1],
                                        acc[2][reg] + bb[2], acc[3][reg] + bb[3]);
                *(float4*)&((float*)outp)[idx * 64 + l15 * 4] = v4;  // packed f32
                uint2 v;
                v.x = cvtpk(v4.x, v4.y);
                v.y = cvtpk(v4.z, v4.w);
                *(uint2*)&out_bf[idx * 64 + l15 * 4] = v;  // packed bf16
            }
        }
    }
}

// ---------- edge step (MFMA + sorted receivers), 1 barrier, 26624 B LDS ----------
// NsNr LDS staging kept: it is the TRANSPOSE that makes the sender/receiver gather
// coalesced (8 consecutive lanes per 128B row). n_bf / e_lat are packed stored-order
// formats; weight rows permuted to match in prep. newe is packed: one float4 write
// per reg; recvbuf lives in stored order. S0: edge embedder fused in.
// LAST: skip residual/LN/e-store.
// Scatter segmentation is REGISTERIZED: receiver IDs live in one reg per lane
// (myr), boundary mask computed once via shfl_down+ballot (SGPR), targets fetched
// via shfl -- replaces ~32 broadcast ds_read_b32 of the old rcvs[] array.
#define EST 72
#define NST 68
template <int S0, int LAST>
__global__ __launch_bounds__(256) void edge_step(
    unsigned short* __restrict__ e_lat, const unsigned short* __restrict__ n_bf,
    const int* __restrict__ ss, const int* __restrict__ rsrt, const int* __restrict__ perm,
    const void* __restrict__ xe_raw, const unsigned short* __restrict__ We0, const void* eb0_,
    const unsigned short* __restrict__ We1, const void* eb1_,
    const unsigned short* __restrict__ We2, const void* eb2_,
    const unsigned short* __restrict__ Wb0, const unsigned short* __restrict__ Wb1,
    const unsigned short* __restrict__ Wb2, const float* __restrict__ b0eff, const void* b1,
    const void* b2, const void* lnsc, const void* lnbi, float* __restrict__ recvbuf, int s,
    const int* __restrict__ flagp) {
    __shared__ __align__(16) unsigned short Ee[64 * EST];     // 9216 B
    __shared__ __align__(16) unsigned short NsNr[128 * NST];  // 17408 B
    float* newe = (float*)NsNr;  // wave w segment: 16 rows x 68 floats (4352 B)

    const int bf = *flagp;
    const int tid = threadIdx.x;
    const long rb = (long)blockIdx.x * 64;
    const int lane = tid & 63, w = tid >> 6, q = lane >> 4, l15 = lane & 15;
    const int arow = 16 * w + l15, aoff = q * 8;
    unsigned short* hw = Ee + w * 16 * EST;  // wave-private h panel (own e rows)

    // ---- wave-private staging: own 16 rows of Ns / Nr (coalesced 128B rows) ----
#pragma unroll
    for (int p = 0; p < 2; p++) {
        int r = 16 * w + p * 8 + (lane >> 3), o = lane & 7;
        long node = ss[rb + r];
        *(uint4*)&NsNr[r * NST + o * 8] = ((const uint4*)(n_bf + node * 64))[o];
    }
#pragma unroll
    for (int p = 0; p < 2; p++) {
        int r = 16 * w + p * 8 + (lane >> 3), o = lane & 7;
        long node = rsrt[rb + r];
        *(uint4*)&NsNr[(64 + r) * NST + o * 8] = ((const uint4*)(n_bf + node * 64))[o];
    }
    // registerized receiver IDs for the scatter epilogue (replaces rcvs[] LDS array)
    const int myr = rsrt[rb + 16 * w + l15];
    // no B1: all reads below touch only own-wave rows

    float ein[4][4];
    f32x4 acc[4];

    if (S0) {
        // ---- inline edge embedder: raw edges [E,4] -> e (ein f32 regs + packed Ee);
        // runs while the NsNr gathers are in flight ----
        zero4(acc);
        {
            bf16x8 a = (bf16x8){0, 0, 0, 0, 0, 0, 0, 0};
            if (q == 0) {
                long src = perm[rb + arow];
                unsigned short u[8] = {0, 0, 0, 0, 0, 0, 0, 0};
#pragma unroll
                for (int j = 0; j < 4; j++) u[j] = f2bf(ldf(xe_raw, src * 4 + j, bf));
                a = *(const bf16x8*)u;
            }
            mfma_chunk(acc, a, We0 + lane * 8);
            float bb[4];
#pragma unroll
            for (int t = 0; t < 4; t++) bb[t] = ldf(eb0_, t * 16 + l15, bf);
#pragma unroll
            for (int reg = 0; reg < 4; reg++) {
                uint2 v;
                v.x = cvtpk(gelu_f(acc[0][reg] + bb[0]), gelu_f(acc[1][reg] + bb[1]));
                v.y = cvtpk(gelu_f(acc[2][reg] + bb[2]), gelu_f(acc[3][reg] + bb[3]));
                *(uint2*)&hw[(q * 4 + reg) * EST + l15 * 4] = v;
            }
        }
        zero4(acc);
        {
#pragma unroll
            for (int c = 0; c < 2; c++) {
                bf16x8 a = *(const bf16x8*)&hw[l15 * EST + c * 32 + aoff];
                mfma_chunk(acc, a, We1 + c * 2048 + lane * 8);
            }
            float bb[4];
#pragma unroll
            for (int t = 0; t < 4; t++) bb[t] = ldf(eb1_, t * 16 + l15, bf);
#pragma unroll
            for (int reg = 0; reg < 4; reg++) {
                uint2 v;
                v.x = cvtpk(gelu_f(acc[0][reg] + bb[0]), gelu_f(acc[1][reg] + bb[1]));
                v.y = cvtpk(gelu_f(acc[2][reg] + bb[2]), gelu_f(acc[3][reg] + bb[3]));
                *(uint2*)&hw[(q * 4 + reg) * EST + l15 * 4] = v;
            }
        }
        zero4(acc);
        {
#pragma unroll
            for (int c = 0; c < 2; c++) {
                bf16x8 a = *(const bf16x8*)&hw[l15 * EST + c * 32 + aoff];
                mfma_chunk(acc, a, We2 + c * 2048 + lane * 8);
            }
            float bb[4];
#pragma unroll
            for (int t = 0; t < 4; t++) bb[t] = ldf(eb2_, t * 16 + l15, bf);
#pragma unroll
            for (int reg = 0; reg < 4; reg++) {
#pragma unroll
                for (int t = 0; t < 4; t++) ein[reg][t] = acc[t][reg] + bb[t];
                uint2 v;
                v.x = cvtpk(ein[reg][0], ein[reg][1]);
                v.y = cvtpk(ein[reg][2], ein[reg][3]);
                *(uint2*)&Ee[(16 * w + q * 4 + reg) * EST + l15 * 4] = v;
            }
        }
    } else {
        // ---- stage own wave's 16 e rows from e_lat (packed format) ----
#pragma unroll
        for (int p = 0; p < 2; p++) {
            int r = 16 * w + p * 8 + (lane >> 3), o = lane & 7;
            *(uint4*)&Ee[r * EST + o * 8] = ((const uint4*)(e_lat + (rb + r) * 64))[o];
        }
        if (!LAST) {  // residual preload: one b64 per row
#pragma unroll
            for (int reg = 0; reg < 4; reg++) {
                uint2 pv = *(const uint2*)&Ee[(16 * w + q * 4 + reg) * EST + l15 * 4];
                ein[reg][0] = __uint_as_float(pv.x << 16);
                ein[reg][1] = __uint_as_float(pv.x & 0xffff0000u);
                ein[reg][2] = __uint_as_float(pv.y << 16);
                ein[reg][3] = __uint_as_float(pv.y & 0xffff0000u);
            }
        }
    }

    zero4(acc);
    {  // layer 0: K=192 from Ee | Ns | Nr (all own-wave rows)
        const unsigned short* B = Wb0 + (long)s * 6 * 2048 + lane * 8;
#pragma unroll
        for (int c = 0; c < 2; c++) {
            bf16x8 a = *(const bf16x8*)&Ee[arow * EST + c * 32 + aoff];
            mfma_chunk(acc, a, B + c * 2048);
        }
#pragma unroll
        for (int c = 0; c < 2; c++) {
            bf16x8 a = *(const bf16x8*)&NsNr[arow * NST + c * 32 + aoff];
            mfma_chunk(acc, a, B + (2 + c) * 2048);
        }
#pragma unroll
        for (int c = 0; c < 2; c++) {
            bf16x8 a = *(const bf16x8*)&NsNr[(64 + arow) * NST + c * 32 + aoff];
            mfma_chunk(acc, a, B + (4 + c) * 2048);
        }
        float bb[4];
#pragma unroll
        for (int t = 0; t < 4; t++) bb[t] = b0eff[s * 64 + t * 16 + l15];
#pragma unroll
        for (int reg = 0; reg < 4; reg++) {
            uint2 v;
            v.x = cvtpk(gelu_f(acc[0][reg] + bb[0]), gelu_f(acc[1][reg] + bb[1]));
            v.y = cvtpk(gelu_f(acc[2][reg] + bb[2]), gelu_f(acc[3][reg] + bb[3]));
            *(uint2*)&hw[(q * 4 + reg) * EST + l15 * 4] = v;
        }
    }
    zero4(acc);
    {  // layer 1 (wave-private h)
        const unsigned short* B = Wb1 + (long)s * 2 * 2048 + lane * 8;
#pragma unroll
        for (int c = 0; c < 2; c++) {
            bf16x8 a = *(const bf16x8*)&hw[l15 * EST + c * 32 + aoff];
            mfma_chunk(acc, a, B + c * 2048);
        }
        float bb[4];
#pragma unroll
        for (int t = 0; t < 4; t++) bb[t] = ldf(b1, (long)s * 64 + t * 16 + l15, bf);
#pragma unroll
        for (int reg = 0; reg < 4; reg++) {
            uint2 v;
            v.x = cvtpk(gelu_f(acc[0][reg] + bb[0]), gelu_f(acc[1][reg] + bb[1]));
            v.y = cvtpk(gelu_f(acc[2][reg] + bb[2]), gelu_f(acc[3][reg] + bb[3]));
            *(uint2*)&hw[(q * 4 + reg) * EST + l15 * 4] = v;
        }
    }
    zero4(acc);
    {  // layer 2
        const unsigned short* B = Wb2 + (long)s * 2 * 2048 + lane * 8;
#pragma unroll
        for (int c = 0; c < 2; c++) {
            bf16x8 a = *(const bf16x8*)&hw[l15 * EST + c * 32 + aoff];
            mfma_chunk(acc, a, B + c * 2048);
        }
    }
    __syncthreads();  // B2: all layer-0 NsNr reads drained before newe overlay

    // ---- fin = new_e + b2 (bias load overlaps layer-2 chain); packed newe ----
    float fin[4][4];
    {
        float bb[4];
#pragma unroll
        for (int t = 0; t < 4; t++) bb[t] = ldf(b2, (long)s * 64 + t * 16 + l15, bf);
#pragma unroll
        for (int reg = 0; reg < 4; reg++)
#pragma unroll
            for (int t = 0; t < 4; t++) fin[reg][t] = acc[t][reg] + bb[t];
    }
    float lsc[4], lbi[4];
    if (!LAST) {
#pragma unroll
        for (int t = 0; t < 4; t++) {
            lsc[t] = ldf(lnsc, (long)s * 64 + t * 16 + l15, bf);
            lbi[t] = ldf(lnbi, (long)s * 64 + t * 16 + l15, bf);
        }
    }
#pragma unroll
    for (int reg = 0; reg < 4; reg++) {
        const int lr = q * 4 + reg;
        // packed stored-order newe row: one b128 instead of 16 b32
        *(float4*)&newe[w * 1088 + lr * 68 + l15 * 4] =
            make_float4(fin[reg][0], fin[reg][1], fin[reg][2], fin[reg][3]);
        if (!LAST) {
            float u[4], ssum = 0.f;
#pragma unroll
            for (int t = 0; t < 4; t++) {
                u[t] = ein[reg][t] + fin[reg][t];
                ssum += u[t];
            }
#pragma unroll
            for (int m = 1; m < 16; m <<= 1) ssum += __shfl_xor(ssum, m, 64);
            const float mu = ssum * (1.0f / 64.0f);
            float d[4], vv = 0.f;
#pragma unroll
            for (int t = 0; t < 4; t++) { d[t] = u[t] - mu; vv += d[t] * d[t]; }
#pragma unroll
            for (int m = 1; m < 16; m <<= 1) vv += __shfl_xor(vv, m, 64);
            const float rs = rsqrtf(vv * (1.0f / 64.0f) + 1e-6f);
            uint2 v;
            v.x = cvtpk(d[0] * rs * lsc[0] + lbi[0], d[1] * rs * lsc[1] + lbi[1]);
            v.y = cvtpk(d[2] * rs * lsc[2] + lbi[2], d[3] * rs * lsc[3] + lbi[3]);
            *(uint2*)&Ee[(16 * w + lr) * EST + l15 * 4] = v;  // packed LN'd e
        }
    }
    // no B3: e-store reads only own-wave Ee rows

    if (!LAST) {  // wave-private vectorized e store (packed format)
#pragma unroll
        for (int p = 0; p < 2; p++) {
            int r = 16 * w + p * 8 + (lane >> 3), o = lane & 7;
            *(uint4*)&e_lat[(rb + r) * 64 + o * 8] = *(const uint4*)&Ee[r * EST + o * 8];
        }
    }
    // ---- run-segmented scatter-add (sorted receivers; own-wave newe rows).
    // Boundary mask in SGPR via ballot; targets via shfl -- zero LDS reads of IDs.
    {
        const int col = tid & 63;
        int nxt = __shfl_down(myr, 1);  // lanes with l15==15 get garbage; masked below
        bool bnd = (l15 == 15) || (nxt != myr);
        unsigned long long bal = __ballot(bnd);
        unsigned mask = (unsigned)bal & 0xFFFFu;  // wave-uniform (quarters replicate)
        float a = 0.f;
#pragma unroll
        for (int rr = 0; rr < 16; rr++) {
            a += newe[w * 1088 + rr * 68 + col];
            if (mask & (1u << rr)) {  // scalar bit-test, wave-uniform branch
                int tgt = __shfl(myr, rr);  // rcvs[16w+rr] from lane rr
                atomicAdd(&recvbuf[(long)tgt * 64 + col], a);
                a = 0.f;
            }
        }
    }
}

// ---------- node update (MFMA), 0 barriers; FINAL fuses the decoder ----------
#define NXS 136
template <int FINAL>
__global__ __launch_bounds__(256) void node_update_mfma(
    float* __restrict__ n_lat, unsigned short* __restrict__ n_bf, float* __restrict__ recvbuf,
    const unsigned short* __restrict__ Wb0, const float* __restrict__ b0eff,
    const unsigned short* __restrict__ Wb1, const void* b1,
    const unsigned short* __restrict__ Wb2, const void* b2, const void* lnsc,
    const void* lnbi, const unsigned short* __restrict__ WbD0, const void* db0,
    const unsigned short* __restrict__ WbD1, const void* db1, const void* dW2,
    const void* db2, void* __restrict__ outp, int s, const int* __restrict__ flagp) {
    __shared__ __align__(16) unsigned short Xs[64 * NXS];   // 17408 B
    __shared__ __align__(16) unsigned short hbuf[64 * 72];  // per-wave panels
    const int bf = *flagp;
    const int tid = threadIdx.x;
    const long rb = (long)blockIdx.x * 64;
    const int lane = tid & 63, w = tid >> 6, q = lane >> 4, l15 = lane & 15;
    const int arow = 16 * w + l15, aoff = q * 8;
    unsigned short* hw = hbuf + w * 16 * 72;

#pragma unroll
    for (int p = 0; p < 2; p++) {
        int r = 16 * w + p * 8 + (lane >> 3), o = lane & 7;
        long idx = rb + r;
        uint4 v = {0u, 0u, 0u, 0u};
        if (idx < N_NODES) v = ((const uint4*)(n_bf + idx * 64))[o];
        *(uint4*)&Xs[r * NXS + o * 8] = v;
    }
#pragma unroll
    for (int p = 0; p < 2; p++) {
        int r = 16 * w + p * 8 + (lane >> 3), o = lane & 7;
        long idx = rb + r;
        uint4 v = {0u, 0u, 0u, 0u};
        if (idx < N_NODES) {
            const float* src = recvbuf + idx * 64 + o * 8;
            float4 x0 = *(const float4*)src, x1 = *(const float4*)(src + 4);
            v.x = cvtpk(x0.x, x0.y);
            v.y = cvtpk(x0.z, x0.w);
            v.z = cvtpk(x1.x, x1.y);
            v.w = cvtpk(x1.z, x1.w);
        }
        *(uint4*)&Xs[r * NXS + 64 + o * 8] = v;
    }
    // no barrier: own-wave rows only

    f32x4 acc[4];
    zero4(acc);
    {  // layer 0: K=128 (glob folded into b0eff)
        const unsigned short* B = Wb0 + (long)s * 4 * 2048 + lane * 8;
#pragma unroll
        for (int c = 0; c < 4; c++) {
            bf16x8 a = *(const bf16x8*)&Xs[arow * NXS + c * 32 + aoff];
            mfma_chunk(acc, a, B + c * 2048);
        }
        float bb[4];
#pragma unroll
        for (int t = 0; t < 4; t++) bb[t] = b0eff[s * 64 + t * 16 + l15];
#pragma unroll
        for (int reg = 0; reg < 4; reg++) {
            uint2 v;
            v.x = cvtpk(gelu_f(acc[0][reg] + bb[0]), gelu_f(acc[1][reg] + bb[1]));
            v.y = cvtpk(gelu_f(acc[2][reg] + bb[2]), gelu_f(acc[3][reg] + bb[3]));
            *(uint2*)&hw[(q * 4 + reg) * 72 + l15 * 4] = v;
        }
    }
    zero4(acc);
    {
        const unsigned short* B = Wb1 + (long)s * 2 * 2048 + lane * 8;
#pragma unroll
        for (int c = 0; c < 2; c++) {
            bf16x8 a = *(const bf16x8*)&hw[l15 * 72 + c * 32 + aoff];
            mfma_chunk(acc, a, B + c * 2048);
        }
        float bb[4];
#pragma unroll
        for (int t = 0; t < 4; t++) bb[t] = ldf(b1, (long)s * 64 + t * 16 + l15, bf);
#pragma unroll
        for (int reg = 0; reg < 4; reg++) {
            uint2 v;
            v.x = cvtpk(gelu_f(acc[0][reg] + bb[0]), gelu_f(acc[1][reg] + bb[1]));
            v.y = cvtpk(gelu_f(acc[2][reg] + bb[2]), gelu_f(acc[3][reg] + bb[3]));
            *(uint2*)&hw[(q * 4 + reg) * 72 + l15 * 4] = v;
        }
    }
    zero4(acc);
    {
        const unsigned short* B = Wb2 + (long)s * 2 * 2048 + lane * 8;
#pragma unroll
        for (int c = 0; c < 2; c++) {
            bf16x8 a = *(const bf16x8*)&hw[l15 * 72 + c * 32 + aoff];
            mfma_chunk(acc, a, B + c * 2048);
        }
    }
    float b2v[4], lsc[4], lbi[4];
#pragma unroll
    for (int t = 0; t < 4; t++) {
        b2v[t] = ldf(b2, (long)s * 64 + t * 16 + l15, bf);
        lsc[t] = ldf(lnsc, (long)s * 64 + t * 16 + l15, bf);
        lbi[t] = ldf(lnbi, (long)s * 64 + t * 16 + l15, bf);
    }
#pragma unroll
    for (int reg = 0; reg < 4; reg++) {
        const int rowl = 16 * w + q * 4 + reg;
        const long idx = rb + rowl;
        const bool valid = idx < N_NODES;
        float4 xn4 = make_float4(0.f, 0.f, 0.f, 0.f);
        if (valid) xn4 = *(const float4*)&n_lat[idx * 64 + l15 * 4];  // packed f32
        float u[4], ssum = 0.f;
        u[0] = xn4.x + acc[0][reg] + b2v[0];
        u[1] = xn4.y + acc[1][reg] + b2v[1];
        u[2] = xn4.z + acc[2][reg] + b2v[2];
        u[3] = xn4.w + acc[3][reg] + b2v[3];
#pragma unroll
        for (int t = 0; t < 4; t++) ssum += u[t];
#pragma unroll
        for (int m = 1; m < 16; m <<= 1) ssum += __shfl_xor(ssum, m, 64);
        const float mu = ssum * (1.0f / 64.0f);
        float d[4], vv = 0.f;
#pragma unroll
        for (int t = 0; t < 4; t++) { d[t] = u[t] - mu; vv += d[t] * d[t]; }
#pragma unroll
        for (int m = 1; m < 16; m <<= 1) vv += __shfl_xor(vv, m, 64);
        const float rs = rsqrtf(vv * (1.0f / 64.0f) + 1e-6f);
        if (FINAL) {
            // n is consumed only by the decoder -> packed panel, no global n stores
            uint2 v;
            v.x = cvtpk(d[0] * rs * lsc[0] + lbi[0], d[1] * rs * lsc[1] + lbi[1]);
            v.y = cvtpk(d[2] * rs * lsc[2] + lbi[2], d[3] * rs * lsc[3] + lbi[3]);
            *(uint2*)&hw[(q * 4 + reg) * 72 + l15 * 4] = v;
        } else if (valid) {
            float4 v4 = make_float4(d[0] * rs * lsc[0] + lbi[0], d[1] * rs * lsc[1] + lbi[1],
                                    d[2] * rs * lsc[2] + lbi[2], d[3] * rs * lsc[3] + lbi[3]);
            *(float4*)&n_lat[idx * 64 + l15 * 4] = v4;  // packed f32
            uint2 v;
            v.x = cvtpk(v4.x, v4.y);
            v.y = cvtpk(v4.z, v4.w);
            *(uint2*)&n_bf[idx * 64 + l15 * 4] = v;  // packed bf16
            *(float4*)&recvbuf[idx * 64 + l15 * 4] = make_float4(0.f, 0.f, 0.f, 0.f);
        }
    }
    if (FINAL) {  // ---- fused decoder: MLP(64,64,64,3) on the packed LN panel ----
        zero4(acc);
        {
#pragma unroll
            for (int c = 0; c < 2; c++) {
                bf16x8 a = *(const bf16x8*)&hw[l15 * 72 + c * 32 + aoff];
                mfma_chunk(acc, a, WbD0 + c * 2048 + lane * 8);
            }
            float bb[4];
#pragma unroll
            for (int t = 0; t < 4; t++) bb[t] = ldf(db0, t * 16 + l15, bf);
#pragma unroll
            for (int reg = 0; reg < 4; reg++) {
                uint2 v;
                v.x = cvtpk(gelu_f(acc[0][reg] + bb[0]), gelu_f(acc[1][reg] + bb[1]));
                v.y = cvtpk(gelu_f(acc[2][reg] + bb[2]), gelu_f(acc[3][reg] + bb[3]));
                *(uint2*)&hw[(q * 4 + reg) * 72 + l15 * 4] = v;
            }
        }
        zero4(acc);
        {
#pragma unroll
            for (int c = 0; c < 2; c++) {
                bf16x8 a = *(const bf16x8*)&hw[l15 * 72 + c * 32 + aoff];
                mfma_chunk(acc, a, WbD1 + c * 2048 + lane * 8);
            }
            float bb[4];
#pragma unroll
            for (int t = 0; t < 4; t++) bb[t] = ldf(db1, t * 16 + l15, bf);
#pragma unroll
            for (int reg = 0; reg < 4; reg++) {
                uint2 v;
                v.x = cvtpk(gelu_f(acc[0][reg] + bb[0]), gelu_f(acc[1][reg] + bb[1]));
                v.y = cvtpk(gelu_f(acc[2][reg] + bb[2]), gelu_f(acc[3][reg] + bb[3]));
                *(uint2*)&hw[(q * 4 + reg) * 72 + l15 * 4] = v;
            }
        }
        const int col = tid & 63;
        const int r0 = w * 16;
        if (col < 3) {
            float a[16];
            const float b = ldf(db2, col, bf);
#pragma unroll
            for (int i = 0; i < 16; i++) a[i] = b;
            for (int k = 0; k < 64; k++) {
                // hw position k holds original feature sigma(k) = 16*(k&3)+(k>>2)
                const int ksrc2 = ((k & 3) << 4) | (k >> 2);
                float wv = ldf(dW2, (long)ksrc2 * 3 + col, bf);
#pragma unroll
                for (int i = 0; i < 16; i++) a[i] = fmaf(bf2f(hw[i * 72 + k]), wv, a[i]);
            }
            for (int i = 0; i < 16; i++) {
                const long idx = rb + r0 + i;
                if (idx < N_NODES) {
                    if (bf)
                        ((unsigned short*)outp)[idx * 3 + col] = f2bf(a[i]);
                    else
                        ((float*)outp)[idx * 3 + col] = a[i];
                }
            }
        }
    }
}

// ---------- launch ----------
extern "C" void kernel_launch(void* const* d_in, const int* in_sizes, int n_in, void* d_out,
                              int out_size, void* d_ws, size_t ws_size, hipStream_t stream) {
    const void* nodes = d_in[0];
    const void* edges = d_in[1];
    const void* glob = d_in[2];
    const void *enW0 = d_in[3], *enb0 = d_in[4], *enW1 = d_in[5], *enb1 = d_in[6],
               *enW2 = d_in[7], *enb2 = d_in[8];
    const void *eeW0 = d_in[9], *eeb0 = d_in[10], *eeW1 = d_in[11], *eeb1 = d_in[12],
               *eeW2 = d_in[13], *eeb2 = d_in[14];
    const void *eW0 = d_in[15], *eb0 = d_in[16], *eW1 = d_in[17], *eb1 = d_in[18],
               *eW2 = d_in[19], *eb2 = d_in[20];
    const void *nW0 = d_in[21], *nb0 = d_in[22], *nW1 = d_in[23], *nb1 = d_in[24],
               *nW2 = d_in[25], *nb2 = d_in[26];
    const void *lnns = d_in[27], *lnnb = d_in[28], *lnes = d_in[29], *lneb = d_in[30];
    const void *dW0 = d_in[31], *db0 = d_in[32], *dW1 = d_in[33], *db1 = d_in[34],
               *dW2 = d_in[35], *db2 = d_in[36];
    const int* senders = (const int*)d_in[37];
    const int* receivers = (const int*)d_in[38];

    // workspace layout
    float* n_lat = (float*)d_ws;               // 3,200,000 f32
    float* recvb = n_lat + 3200000;            // 3,200,000 f32
    float* b0eff_e = recvb + 3200000;          // 192
    float* b0eff_n = b0eff_e + 192;            // 192
    int* flag = (int*)(b0eff_n + 192);         // pad to 64 f32
    unsigned short* e_lat = (unsigned short*)(b0eff_n + 256);  // 51,200,000 bf16
    unsigned short* n_bf = e_lat + 51200000;   // 3,200,000 bf16
    unsigned short* WbBase = n_bf + 3200000;   // 139,264 bf16
    unsigned short* WbE0 = WbBase;
    unsigned short* WbE1 = WbBase + 36864;
    unsigned short* WbE2 = WbBase + 49152;
    unsigned short* WbN0 = WbBase + 61440;
    unsigned short* WbN1 = WbBase + 86016;
    unsigned short* WbN2 = WbBase + 98304;
    unsigned short* WbNE0 = WbBase + 110592;
    unsigned short* WbNE1 = WbBase + 112640;
    unsigned short* WbNE2 = WbBase + 116736;
    unsigned short* WbEE0 = WbBase + 120832;
    unsigned short* WbEE1 = WbBase + 122880;
    unsigned short* WbEE2 = WbBase + 126976;
    unsigned short* WbD0 = WbBase + 131072;
    unsigned short* WbD1 = WbBase + 135168;
    int* counts = (int*)(WbBase + 139264 + 64);  // aligned scratch
    int* sbase = counts + N_NODES;
    int* cursor = sbase + N_NODES;
    int* blockSums = cursor + N_NODES;  // 256
    int* tops = blockSums + 256;        // 256
    int* ss = tops + 256;               // N_EDGES
    int* rsrt = ss + N_EDGES;           // N_EDGES
    int* perm = rsrt + N_EDGES;         // N_EDGES

    detect_kernel<<<1, 64, 0, stream>>>(lnns, flag);

    PrepPtrs pp;
    pp.W[0] = eW0;  pp.W[1] = eW1;  pp.W[2] = eW2;
    pp.W[3] = nW0;  pp.W[4] = nW1;  pp.W[5] = nW2;
    pp.W[6] = enW0; pp.W[7] = enW1; pp.W[8] = enW2;
    pp.W[9] = eeW0; pp.W[10] = eeW1; pp.W[11] = eeW2;
    pp.W[12] = dW0; pp.W[13] = dW1;
    pp.eb0 = eb0; pp.nb0 = nb0; pp.glob = glob;
    prep_all<<<(PREP_WTOTAL + 384 + 255) / 256, 256, 0, stream>>>(pp, WbBase, b0eff_e, b0eff_n,
                                                                  flag);
    hipMemsetAsync(recvb, 0, (size_t)N_NODES * 64 * sizeof(float), stream);
    hipMemsetAsync(counts, 0, (size_t)N_NODES * sizeof(int), stream);

    // counting sort of edges by receiver
    hist_kernel<<<(N_EDGES + 255) / 256, 256, 0, stream>>>(receivers, counts);
    scan_partial<<<NBLK_SCAN, 256, 0, stream>>>(counts, sbase, blockSums);
    scan_tops<<<1, 256, 0, stream>>>(blockSums, tops);
    scan_add<<<NBLK_SCAN, 256, 0, stream>>>(sbase, tops, cursor);
    scatter_kernel<<<(N_EDGES + 255) / 256, 256, 0, stream>>>(senders, receivers, cursor, ss,
                                                              rsrt, perm);

    embed_mfma<7, 0><<<(N_NODES + 63) / 64, 256, 0, stream>>>(
        nodes, WbNE0, enb0, WbNE1, enb1, WbNE2, enb2, n_lat, n_bf, (const int*)nullptr,
        N_NODES, flag);

    // step 0: edge embedder fused into the edge update (no e_lat read, residual in f32)
    edge_step<1, 0><<<N_EDGES / 64, 256, 0, stream>>>(
        e_lat, n_bf, ss, rsrt, perm, edges, WbEE0, eeb0, WbEE1, eeb1, WbEE2, eeb2,
        WbE0, WbE1, WbE2, b0eff_e, eb1, eb2, lnes, lneb, recvb, 0, flag);
    node_update_mfma<0><<<(N_NODES + 63) / 64, 256, 0, stream>>>(
        n_lat, n_bf, recvb, WbN0, b0eff_n, WbN1, nb1, WbN2, nb2, lnns, lnnb,
        nullptr, nullptr, nullptr, nullptr, nullptr, nullptr, nullptr, 0, flag);

    edge_step<0, 0><<<N_EDGES / 64, 256, 0, stream>>>(
        e_lat, n_bf, ss, rsrt, perm, edges, WbEE0, eeb0, WbEE1, eeb1, WbEE2, eeb2,
        WbE0, WbE1, WbE2, b0eff_e, eb1, eb2, lnes, lneb, recvb, 1, flag);
    node_update_mfma<0><<<(N_NODES + 63) / 64, 256, 0, stream>>>(
        n_lat, n_bf, recvb, WbN0, b0eff_n, WbN1, nb1, WbN2, nb2, lnns, lnnb,
        nullptr, nullptr, nullptr, nullptr, nullptr, nullptr, nullptr, 1, flag);

    // step 2: e is dead after this step -> no LN/e-store; decoder fused into node update
    edge_step<0, 1><<<N_EDGES / 64, 256, 0, stream>>>(
        e_lat, n_bf, ss, rsrt, perm, edges, WbEE0, eeb0, WbEE1, eeb1, WbEE2, eeb2,
        WbE0, WbE1, WbE2, b0eff_e, eb1, eb2, lnes, lneb, recvb, 2, flag);
    node_update_mfma<1><<<(N_NODES + 63) / 64, 256, 0, stream>>>(
        n_lat, n_bf, recvb, WbN0, b0eff_n, WbN1, nb1, WbN2, nb2, lnns, lnnb,
        WbD0, db0, WbD1, db1, dW2, db2, d_out, 2, flag);
}